// Round 2
// baseline (3074.418 us; speedup 1.0000x reference)
//
#include <hip/hip_runtime.h>
#include <hip/hip_fp16.h>

typedef unsigned short ushort_t;
typedef _Float16 h8v __attribute__((ext_vector_type(8)));
typedef float f4v __attribute__((ext_vector_type(4)));

#define N_NODES 50000
#define N_EDGES 1600000
#define NB      64
#define HF      128
#define LF      64
#define NC      6
#define EPSBN   1e-5f
#define NBUCK   196          // dst buckets of 256 nodes
#define CAPB    9216         // per-bucket padded capacity
#define EPB     2048         // edges per pass1 block
#define NB64    782          // dst buckets of 64 nodes
#define CAP64   2560         // per-64-bucket capacity (mean 2048, +11 sigma)

// output element offsets (fp32 out confirmed in round 3)
#define OPRED_OFF 0
#define OMU_OFF   384
#define OLV_OFF   3200384
#define ONOI_OFF  6400384

__device__ __forceinline__ int clampi(int v, int lo, int hi) {
    return v < lo ? lo : (v > hi ? hi : v);
}

// ============ init: detect int width, zero counters/pools, fold BN, swizzle weights ============
__global__ void init_k(const int* ei_raw, int* flags,
                       int* bcnt, float* gpool, float* zsum, float* cnt, float* red,
                       _Float16* W2sw, _Float16* Wcsw, _Float16* Wasw,
                       float* bcat, float* sc1, float* sh1, float* sc2, float* sh2,
                       const float* W2,
                       const float* Wmu, const float* bmu, const float* Wlv, const float* blv,
                       const float* Wa1,
                       const float* g1, const float* be1, const float* rm1, const float* rv1,
                       const float* g2, const float* be2, const float* rm2, const float* rv2) {
    int i = blockIdx.x * 256 + threadIdx.x;
    if (blockIdx.x == 0) {
        __shared__ int c1s;
        if (threadIdx.x == 0) c1s = 0;
        __syncthreads();
        if (ei_raw[2 * threadIdx.x + 1] != 0) atomicAdd(&c1s, 1);
        __syncthreads();
        if (threadIdx.x == 0) flags[1] = (c1s == 0) ? 1 : 0;
    }
    if (i < NBUCK) bcnt[i] = 0;
    if (i < NB * LF) { gpool[i] = 0.f; zsum[i] = 0.f; }
    if (i < NB) cnt[i] = 0.f;
    if (i < 4) red[i] = 0.f;
    if (i < HF * HF) {
        int k = i >> 7, c = i & 127;
        int idx = ((k >> 5) * 128 + c) * 32 + (k & 31);
        W2sw[idx] = (_Float16)W2[i];
        float wc = (c < 64) ? Wmu[k * 64 + c] : Wlv[k * 64 + (c - 64)];
        Wcsw[idx] = (_Float16)wc;
    }
    if (i < LF * HF) {
        int k = i >> 7, c = i & 127;
        int idx = ((k >> 5) * 128 + c) * 32 + (k & 31);
        Wasw[idx] = (_Float16)Wa1[i];
    }
    if (i < HF) {
        bcat[i] = (i < 64) ? bmu[i] : blv[i - 64];
        float s1 = g1[i] * rsqrtf(rv1[i] + EPSBN);
        sc1[i] = s1; sh1[i] = be1[i] - rm1[i] * s1;
        float s2 = g2[i] * rsqrtf(rv2[i] + EPSBN);
        sc2[i] = s2; sh2[i] = be2[i] - rm2[i] * s2;
    }
}

// ============ fold input layer into GCN-1 linear: Weff = Win@W1, beff = bin@W1 + b1 ============
__global__ __launch_bounds__(256) void weff_k(const float* __restrict__ Win,
                                              const float* __restrict__ bin,
                                              const float* __restrict__ W1,
                                              const float* __restrict__ b1,
                                              float* __restrict__ Weff,
                                              float* __restrict__ beff) {
    int i = blockIdx.x * 256 + threadIdx.x;
    if (i < 16 * 128) {
        int k = i >> 7, c = i & 127;
        float acc = 0.f;
        for (int j = 0; j < 128; j++) acc += Win[k * 128 + j] * W1[j * 128 + c];
        Weff[i] = acc;
    }
    if (i < 128) {
        float acc = b1[i];
        for (int j = 0; j < 128; j++) acc += bin[j] * W1[j * 128 + i];
        beff[i] = acc;
    }
}

// ============ pass 1: block-local LDS counting sort + run-append to padded buckets ============
__global__ __launch_bounds__(256) void pass1_k(const int* __restrict__ ei,
                                               const float* __restrict__ ew,
                                               int* __restrict__ bcnt,
                                               uint2* __restrict__ recP,
                                               const int* __restrict__ flags) {
    __shared__ uint2 stg[EPB];
    __shared__ int lh[NBUCK];
    __shared__ int lcur[NBUCK];
    __shared__ int gb[NBUCK];
    __shared__ int loff[256];
    int tid = threadIdx.x;
    for (int i = tid; i < NBUCK; i += 256) lh[i] = 0;
    __syncthreads();
    int e0 = blockIdx.x * EPB;
    int i64 = flags[1];
    uint2 myrec[8]; int myb[8];
#pragma unroll
    for (int j = 0; j < 8; j++) {
        int e = e0 + j * 256 + tid;
        if (e < N_EDGES) {
            int di = N_EDGES + e;
            int s = clampi(ei[i64 ? 2 * e : e], 0, N_NODES - 1);
            int d = clampi(ei[i64 ? 2 * di : di], 0, N_NODES - 1);
            myrec[j] = make_uint2((unsigned)s | ((unsigned)d << 16), __float_as_uint(ew[e]));
            myb[j] = d >> 8;
            atomicAdd(&lh[myb[j]], 1);
        } else myb[j] = -1;
    }
    __syncthreads();
    loff[tid] = (tid < NBUCK) ? lh[tid] : 0;
    __syncthreads();
    for (int dth = 1; dth < 256; dth <<= 1) {
        int x = (tid >= dth) ? loff[tid - dth] : 0;
        __syncthreads();
        loff[tid] += x;
        __syncthreads();
    }
    if (tid < NBUCK) lcur[tid] = loff[tid] - lh[tid];
    __syncthreads();
#pragma unroll
    for (int j = 0; j < 8; j++) {
        if (myb[j] >= 0) {
            int p = atomicAdd(&lcur[myb[j]], 1);
            stg[p] = myrec[j];
        }
    }
    if (tid < NBUCK) {
        int c = lh[tid];
        gb[tid] = (c > 0) ? atomicAdd(&bcnt[tid], c) : 0;
    }
    __syncthreads();
    int total = N_EDGES - e0; if (total > EPB) total = EPB;
    for (int idx = tid; idx < total; idx += 256) {
        uint2 r = stg[idx];
        int b = (int)(r.x >> 24);
        int within = idx - (loff[b] - lh[b]);
        int pos = gb[b] + within;
        if (pos < CAPB) recP[b * CAPB + pos] = r;
    }
}

// ============ pass 2a: per-bucket hist + degree -> nodeInfo (start|cnt packed), dinv ============
// nodeInfo[n] = (b*CAPB + excl) | (cnt << 21);  start is padded recP/epack coords (21 bits).
__global__ __launch_bounds__(256) void pass2a_k(const uint2* __restrict__ recP,
                                                const int* __restrict__ bcnt,
                                                unsigned* __restrict__ nodeInfo,
                                                float* __restrict__ dinv) {
    __shared__ int cnt[256];
    __shared__ float degs[256];
    __shared__ int off[256];
    int b = blockIdx.x, t = threadIdx.x;
    cnt[t] = 0; degs[t] = 0.f;
    __syncthreads();
    int cb = bcnt[b]; if (cb > CAPB) cb = CAPB;
    int n0 = b * CAPB;
    for (int i = t; i < cb; i += 256) {
        uint2 r = recP[n0 + i];
        int dl = (r.x >> 16) & 255;
        atomicAdd(&cnt[dl], 1);
        atomicAdd(&degs[dl], __uint_as_float(r.y));
    }
    __syncthreads();
    int v = cnt[t];
    off[t] = v;
    __syncthreads();
    for (int dth = 1; dth < 256; dth <<= 1) {
        int x = (t >= dth) ? off[t - dth] : 0;
        __syncthreads();
        off[t] += x;
        __syncthreads();
    }
    int excl = off[t] - v;
    int n = (b << 8) + t;
    if (n < N_NODES) {
        int cv = v > 2047 ? 2047 : v;
        nodeInfo[n] = (unsigned)(n0 + excl) | ((unsigned)cv << 21);
        dinv[n] = rsqrtf(1.f + degs[t]);
    }
}

// ============ pass 2b: in-bucket sort into packed 4B records: src | fp16(ew)<<16 ============
__global__ __launch_bounds__(256) void pass2b_k(const uint2* __restrict__ recP,
                                                const int* __restrict__ bcnt,
                                                const unsigned* __restrict__ nodeInfo,
                                                unsigned* __restrict__ epack) {
    __shared__ int cur[256];
    int b = blockIdx.x, t = threadIdx.x;
    int n = (b << 8) + t;
    cur[t] = (n < N_NODES) ? (int)(nodeInfo[n] & 0x1FFFFFu) : 0;
    __syncthreads();
    int cb = bcnt[b]; if (cb > CAPB) cb = CAPB;
    int n0 = b * CAPB;
    for (int i = t; i < cb; i += 256) {
        uint2 r = recP[n0 + i];
        int s = (int)(r.x & 0xFFFFu);
        int dl = (r.x >> 16) & 255;
        int p = atomicAdd(&cur[dl], 1);
        __half hw = __float2half(__uint_as_float(r.y));
        epack[p] = (unsigned)s | ((unsigned)__half_as_ushort(hw) << 16);
    }
}

// ============ pass 2c: split each 256-bucket into 4x 64-node sub-buckets, SORTED BY src>>8 ============
// recS record: src | (dst&63)<<16, ew fp32.  Lists zero-padded to a multiple of 64 (<= CAP64).
// Sorting by src creates a chip-wide ascending src sweep in aggB -> L2-window locality.
__global__ __launch_bounds__(256) void pass2c_k(const uint2* __restrict__ recP,
                                                const int* __restrict__ bcnt,
                                                uint2* __restrict__ recS,
                                                int* __restrict__ bcnt2) {
    __shared__ int hist[784];     // key = sub*196 + (src>>8)
    __shared__ int csum[256];
    __shared__ int subS[5];
    __shared__ int rawS[4];
    int b = blockIdx.x, t = threadIdx.x;
    for (int i = t; i < 784; i += 256) hist[i] = 0;
    __syncthreads();
    int cb = bcnt[b]; if (cb > CAPB) cb = CAPB;
    int n0 = b * CAPB;
    for (int i = t; i < cb; i += 256) {
        unsigned x = recP[n0 + i].x;
        int d = (int)(x >> 16), s = (int)(x & 0xFFFFu);
        atomicAdd(&hist[((d >> 6) & 3) * 196 + (s >> 8)], 1);
    }
    __syncthreads();
    int i0 = 4 * t;
    int h0 = (i0 + 0 < 784) ? hist[i0 + 0] : 0;
    int h1 = (i0 + 1 < 784) ? hist[i0 + 1] : 0;
    int h2 = (i0 + 2 < 784) ? hist[i0 + 2] : 0;
    int h3 = (i0 + 3 < 784) ? hist[i0 + 3] : 0;
    int sum = h0 + h1 + h2 + h3;
    csum[t] = sum;
    __syncthreads();
    for (int dth = 1; dth < 256; dth <<= 1) {
        int x = (t >= dth) ? csum[t - dth] : 0;
        __syncthreads();
        csum[t] += x;
        __syncthreads();
    }
    int run = csum[t] - sum;
    if (i0 + 0 < 784) hist[i0 + 0] = run; run += h0;
    if (i0 + 1 < 784) hist[i0 + 1] = run; run += h1;
    if (i0 + 2 < 784) hist[i0 + 2] = run; run += h2;
    if (i0 + 3 < 784) hist[i0 + 3] = run;
    __syncthreads();
    if (t < 4) subS[t] = hist[t * 196];
    if (t == 4) subS[4] = cb;
    __syncthreads();
    for (int i = t; i < cb; i += 256) {
        uint2 r = recP[n0 + i];
        int d = (int)(r.x >> 16), s = (int)(r.x & 0xFFFFu);
        int sub = (d >> 6) & 3;
        int p = atomicAdd(&hist[sub * 196 + (s >> 8)], 1);
        int local = p - subS[sub];
        if (local < CAP64)
            recS[(size_t)(b * 4 + sub) * CAP64 + local] =
                make_uint2((unsigned)s | ((unsigned)(d & 63) << 16), r.y);
    }
    if (t < 4) {
        int raw = subS[t + 1] - subS[t];
        if (raw > CAP64) raw = CAP64;
        rawS[t] = raw;
        bcnt2[b * 4 + t] = (raw + 63) & ~63;
    }
    __syncthreads();
    for (int sub = 0; sub < 4; sub++) {
        int raw = rawS[sub];
        int pad = (raw + 63) & ~63;
        for (int i = raw + t; i < pad; i += 256)
            recS[(size_t)(b * 4 + sub) * CAP64 + i] = make_uint2(0u, 0u);
    }
}

// ============ agg16: 16-dim aggregation of raw x (pre-linear), 8 lanes per node ============
// aggx[d] = dinv_d * (sum_e ew*dinv_s*x[s] + dinv_d*x[d]);  Sd = dinv_d*(sum ew*dinv_s + dinv_d)
__global__ __launch_bounds__(256) void agg16_k(const float* __restrict__ x,
                                               const unsigned* __restrict__ epack,
                                               const unsigned* __restrict__ nodeInfo,
                                               const float* __restrict__ dinv,
                                               __half* __restrict__ aggx,
                                               float* __restrict__ Sd) {
    int tid = threadIdx.x;
    int n = blockIdx.x * 32 + (tid >> 3);
    if (n >= N_NODES) return;
    int f = tid & 7;
    unsigned info = nodeInfo[n];
    int e0 = (int)(info & 0x1FFFFFu);
    int e1 = e0 + (int)(info >> 21);
    float dv = dinv[n];
    float2 xs = *(const float2*)(x + n * 16 + f * 2);
    float ax = dv * xs.x, ay = dv * xs.y;
    float ss = dv;
    int e = e0;
    for (; e + 8 <= e1; e += 8) {
        unsigned r[8];
#pragma unroll
        for (int j = 0; j < 8; j++) r[j] = epack[e + j];
        float2 v[8]; float w[8];
#pragma unroll
        for (int j = 0; j < 8; j++) {
            int s = (int)(r[j] & 0xFFFFu);
            w[j] = __half2float(__ushort_as_half((ushort_t)(r[j] >> 16))) * dinv[s];
            v[j] = *(const float2*)(x + s * 16 + f * 2);
        }
#pragma unroll
        for (int j = 0; j < 8; j++) {
            ax += w[j] * v[j].x; ay += w[j] * v[j].y; ss += w[j];
        }
    }
    for (; e < e1; e++) {
        unsigned r = epack[e];
        int s = (int)(r & 0xFFFFu);
        float w = __half2float(__ushort_as_half((ushort_t)(r >> 16))) * dinv[s];
        float2 v = *(const float2*)(x + s * 16 + f * 2);
        ax += w * v.x; ay += w * v.y; ss += w;
    }
    *(__half2*)(aggx + n * 16 + 2 * f) = __floats2half2_rn(ax * dv, ay * dv);
    if (f == 0) Sd[n] = dv * ss;
}

// ============ layer-1 linear + BN + ReLU: h1 = relu(sc1*(aggx@Weff + Sd*beff) + sh1) ============
__global__ __launch_bounds__(128) void gemmbn_k(const __half* __restrict__ aggx,
                                                const float* __restrict__ Sd,
                                                const float* __restrict__ Weff,
                                                const float* __restrict__ beff,
                                                const float* __restrict__ sc1,
                                                const float* __restrict__ sh1,
                                                __half* __restrict__ out) {
    __shared__ float xl[16 * 16];
    __shared__ float sdl[16];
    int tid = threadIdx.x;
    int row0 = blockIdx.x * 16;
    if (tid < 64) {
        int r = tid >> 2, k4 = tid & 3;
        int row = row0 + r;
        float4 v4 = make_float4(0.f, 0.f, 0.f, 0.f);
        if (row < N_NODES) {
            __half2 h0 = *(const __half2*)(aggx + row * 16 + k4 * 4);
            __half2 h1 = *(const __half2*)(aggx + row * 16 + k4 * 4 + 2);
            float2 f0 = __half22float2(h0), f1 = __half22float2(h1);
            v4 = make_float4(f0.x, f0.y, f1.x, f1.y);
        }
        *(float4*)(xl + r * 16 + k4 * 4) = v4;
    }
    if (tid < 16) {
        int row = row0 + tid;
        sdl[tid] = (row < N_NODES) ? Sd[row] : 0.f;
    }
    float wv[16];
#pragma unroll
    for (int k = 0; k < 16; k++) wv[k] = Weff[k * 128 + tid];
    float bias = beff[tid];
    float s1 = sc1[tid], h1v = sh1[tid];
    __syncthreads();
    for (int r = 0; r < 16; r++) {
        float acc = sdl[r] * bias;
#pragma unroll
        for (int k = 0; k < 16; k++) acc += xl[r * 16 + k] * wv[k];
        int row = row0 + r;
        if (row < N_NODES) {
            float o = fmaxf(acc * s1 + h1v, 0.f);
            out[row * 128 + tid] = __float2half(o);
        }
    }
}

// ============ MFMA GEMM: in(fp16)[N,128] @ Wsw + b, epilogue scales rows by dinv -> fp16 ============
__global__ __launch_bounds__(256) void gemm128_k(const __half* __restrict__ in,
                                                 const _Float16* __restrict__ Wsw,
                                                 const float* __restrict__ b,
                                                 const float* __restrict__ dinv,
                                                 __half* __restrict__ out) {
    int l = threadIdx.x & 63, w = threadIdx.x >> 6;
    int row0 = blockIdx.x * 64 + w * 16;
    int m = l & 15, q = l >> 4;
    int row = row0 + m;
    bool rok = row < N_NODES;
    const h8v* inp = (const h8v*)in;
    const h8v* wp = (const h8v*)Wsw;
    h8v az = {0, 0, 0, 0, 0, 0, 0, 0};
    h8v a[4];
#pragma unroll
    for (int kb = 0; kb < 4; kb++)
        a[kb] = rok ? inp[(row * 128 + kb * 32 + q * 8) >> 3] : az;
    float dv4[4];
#pragma unroll
    for (int r = 0; r < 4; r++) {
        int orow = row0 + q * 4 + r;
        dv4[r] = (orow < N_NODES) ? dinv[orow] : 0.f;
    }
#pragma unroll
    for (int ct = 0; ct < 8; ct++) {
        f4v acc = {0.f, 0.f, 0.f, 0.f};
#pragma unroll
        for (int kb = 0; kb < 4; kb++) {
            h8v bf = wp[((kb * 128 + ct * 16 + m) * 32 + q * 8) >> 3];
            acc = __builtin_amdgcn_mfma_f32_16x16x32_f16(a[kb], bf, acc, 0, 0, 0);
        }
        int col = ct * 16 + m;
        float bias = b[col];
#pragma unroll
        for (int r = 0; r < 4; r++) {
            int orow = row0 + q * 4 + r;
            if (orow < N_NODES) out[orow * 128 + col] = __float2half((acc[r] + bias) * dv4[r]);
        }
    }
}

// ============ push-style bucket aggregation: one block per 64-dst-node bucket ============
// acc[dl][f] += ew * t[src][f]  (LDS fp32 atomics, src-sorted sweep for L2 locality)
// epilogue: out = dv*(acc + t[d]);  MODE 0: +BN+ReLU -> fp16.  MODE 1: mu/lv fp32 + zh fp16.
template <int MODE>
__global__ __launch_bounds__(256) void aggB_k(const __half* __restrict__ lin,
                                              const uint2* __restrict__ recS,
                                              const int* __restrict__ bcnt2,
                                              const float* __restrict__ dinv,
                                              const float* __restrict__ sc,
                                              const float* __restrict__ sh,
                                              __half* __restrict__ outH,
                                              __half* __restrict__ zh,
                                              float* __restrict__ outp) {
    __shared__ __align__(16) float acc[64 * 128];    // 32 KB
    int t = threadIdx.x, l = t & 63, wv = t >> 6;
    int b = blockIdx.x;
#pragma unroll
    for (int i = 0; i < 8; i++)
        *(float4*)(acc + 4 * (t + 256 * i)) = make_float4(0.f, 0.f, 0.f, 0.f);
    __syncthreads();
    int cb = bcnt2[b];                               // padded multiple of 64, <= CAP64
    const uint2* rp = recS + (size_t)b * CAP64;
    const __half2* linv = (const __half2*)lin;
    float* accl = acc + 2 * l;
    for (int c0 = wv * 64; c0 < cb; c0 += 256) {
        uint2 rec = rp[c0 + l];                      // lane-coalesced 512B record load
#pragma unroll
        for (int j0 = 0; j0 < 64; j0 += 8) {
            unsigned rx[8], ry[8];
#pragma unroll
            for (int jj = 0; jj < 8; jj++) {
                rx[jj] = __builtin_amdgcn_readlane(rec.x, j0 + jj);
                ry[jj] = __builtin_amdgcn_readlane(rec.y, j0 + jj);
            }
            __half2 v[8];
#pragma unroll
            for (int jj = 0; jj < 8; jj++)
                v[jj] = linv[(int)(rx[jj] & 0xFFFFu) * 64 + l];   // 256B wave gather
#pragma unroll
            for (int jj = 0; jj < 8; jj++) {
                float w = __uint_as_float(ry[jj]);
                float2 f = __half22float2(v[jj]);
                float* ap = accl + ((rx[jj] >> 16) & 63u) * 128;
                atomicAdd(ap, w * f.x);              // ds_add_f32, 2-way aliasing = free
                atomicAdd(ap + 1, w * f.y);
            }
        }
    }
    __syncthreads();
    int n0 = b << 6;
    for (int nd = wv; nd < 64; nd += 4) {
        int n = n0 + nd;
        if (n >= N_NODES) break;
        float2 a = *(float2*)(acc + nd * 128 + 2 * l);
        float2 self = __half22float2(linv[n * 64 + l]);
        float dv = dinv[n];
        float ax = (a.x + self.x) * dv, ay = (a.y + self.y) * dv;
        if (MODE == 0) {
            float2 s2 = *(const float2*)(sc + 2 * l);
            float2 h2 = *(const float2*)(sh + 2 * l);
            float o0 = fmaxf(ax * s2.x + h2.x, 0.f);
            float o1 = fmaxf(ay * s2.y + h2.y, 0.f);
            *(__half2*)(outH + n * 128 + 2 * l) = __floats2half2_rn(o0, o1);
        } else {
            if (l < 32) {
                *(float2*)(outp + OMU_OFF + n * 64 + 2 * l) = make_float2(ax, ay);
                ((__half2*)zh)[n * 32 + l] = __floats2half2_rn(ax, ay);
            } else {
                *(float2*)(outp + OLV_OFF + n * 64 + (2 * l - 64)) = make_float2(ax, ay);
            }
        }
    }
}

// ============ attention via MFMA: p = exp(tanh(zh @ Wa1 + ba1) @ Wa2 + ba2) ============
__global__ __launch_bounds__(256) void att_k(const __half* __restrict__ zh,
                                             const _Float16* __restrict__ Wasw,
                                             const float* __restrict__ ba1,
                                             const float* __restrict__ Wa2,
                                             const float* __restrict__ ba2,
                                             float* __restrict__ p, float* __restrict__ red) {
    __shared__ float rsum[4];
    int l = threadIdx.x & 63, w = threadIdx.x >> 6;
    int row0 = blockIdx.x * 64 + w * 16;
    int m = l & 15, q = l >> 4;
    int row = row0 + m;
    bool rok = row < N_NODES;
    const h8v* zp = (const h8v*)zh;
    const h8v* wp = (const h8v*)Wasw;
    h8v az = {0, 0, 0, 0, 0, 0, 0, 0};
    h8v a[2];
#pragma unroll
    for (int kb = 0; kb < 2; kb++)
        a[kb] = rok ? zp[(row * 64 + kb * 32 + q * 8) >> 3] : az;
    float ysum[4] = {0.f, 0.f, 0.f, 0.f};
#pragma unroll
    for (int ct = 0; ct < 8; ct++) {
        f4v acc = {0.f, 0.f, 0.f, 0.f};
#pragma unroll
        for (int kb = 0; kb < 2; kb++) {
            h8v bf = wp[((kb * 128 + ct * 16 + m) * 32 + q * 8) >> 3];
            acc = __builtin_amdgcn_mfma_f32_16x16x32_f16(a[kb], bf, acc, 0, 0, 0);
        }
        int col = ct * 16 + m;
        float bb = ba1[col], wa2 = Wa2[col];
#pragma unroll
        for (int r = 0; r < 4; r++) ysum[r] += tanhf(acc[r] + bb) * wa2;
    }
#pragma unroll
    for (int off = 1; off < 16; off <<= 1) {
#pragma unroll
        for (int r = 0; r < 4; r++) ysum[r] += __shfl_xor(ysum[r], off, 64);
    }
    float wsum = 0.f;
    if (m == 0) {
        float ba2v = ba2[0];
#pragma unroll
        for (int r = 0; r < 4; r++) {
            int orow = row0 + q * 4 + r;
            if (orow < N_NODES) {
                float pe = expf(ysum[r] + ba2v);
                p[orow] = pe;
                wsum += pe;
            }
        }
    }
    wsum += __shfl_xor(wsum, 16, 64);
    wsum += __shfl_xor(wsum, 32, 64);
    if (l == 0) rsum[w] = wsum;
    __syncthreads();
    if (threadIdx.x == 0)
        atomicAdd(&red[1], rsum[0] + rsum[1] + rsum[2] + rsum[3]);
}

// ============ pooling (4 groups of 64 per block) ============
__global__ __launch_bounds__(256) void pool_k(const __half* __restrict__ zh,
                                              const float* __restrict__ p,
                                              const int* __restrict__ batch,
                                              float* gpool, float* zsum, float* cnt,
                                              const int* __restrict__ flags) {
    int l = threadIdx.x & 63, g = threadIdx.x >> 6;
    int i64 = flags[1];
    int nstart = blockIdx.x * 256 + g * 64;
    float ag = 0.f, az = 0.f, c = 0.f;
    int cur = -1;
    for (int i = 0; i < 64; i++) {
        int n = nstart + i;
        if (n >= N_NODES) break;
        int b = clampi(batch[i64 ? 2 * n : n], 0, NB - 1);
        if (b != cur) {
            if (cur >= 0) {
                atomicAdd(&gpool[cur * 64 + l], ag);
                atomicAdd(&zsum[cur * 64 + l], az);
                if (l == 0) atomicAdd(&cnt[cur], c);
            }
            cur = b; ag = 0.f; az = 0.f; c = 0.f;
        }
        float pe = p[n];
        float zv = __half2float(zh[n * 64 + l]);
        ag += pe * zv; az += zv; c += 1.f;
    }
    if (cur >= 0) {
        atomicAdd(&gpool[cur * 64 + l], ag);
        atomicAdd(&zsum[cur * 64 + l], az);
        if (l == 0) atomicAdd(&cnt[cur], c);
    }
}

// ============ per-graph heads ============
__global__ __launch_bounds__(128) void head_k(const float* __restrict__ gpool,
                                              const float* __restrict__ zsum,
                                              const float* __restrict__ cnt,
                                              const float* __restrict__ red,
                                              const float* Wc1, const float* bc1,
                                              const float* Wc2, const float* bc2,
                                              const float* Wc3, const float* bc3,
                                              const float* Wn1, const float* bn1,
                                              const float* Wn2, const float* bn2,
                                              float* __restrict__ outp) {
    __shared__ float gsh[64], zm[64], p1[128], p2[64], n1[64];
    int b = blockIdx.x, t = threadIdx.x;
    float S = red[1];
    if (t < 64) {
        gsh[t] = gpool[b * 64 + t] / S;
        zm[t] = zsum[b * 64 + t] / fmaxf(cnt[b], 1.f);
    }
    __syncthreads();
    {
        float acc = bc1[t];
        for (int k = 0; k < 64; k++) acc += gsh[k] * Wc1[k * 128 + t];
        p1[t] = fmaxf(acc, 0.f);
    }
    __syncthreads();
    if (t < 64) {
        float acc = bc2[t];
        for (int k = 0; k < 128; k++) acc += p1[k] * Wc2[k * 64 + t];
        p2[t] = fmaxf(acc, 0.f);
    } else {
        int tt = t - 64;
        float acc = bn1[tt];
        for (int k = 0; k < 64; k++) acc += zm[k] * Wn1[k * 64 + tt];
        n1[tt] = fmaxf(acc, 0.f);
    }
    __syncthreads();
    if (t < NC) {
        float acc = bc3[t];
        for (int k = 0; k < 64; k++) acc += p2[k] * Wc3[k * 6 + t];
        outp[OPRED_OFF + b * 6 + t] = acc;
    }
    if (t == 64) {
        float acc = bn2[0];
        for (int k = 0; k < 64; k++) acc += n1[k] * Wn2[k];
        outp[ONOI_OFF + b] = 1.f / (1.f + expf(-acc));
    }
}

extern "C" void kernel_launch(void* const* d_in, const int* in_sizes, int n_in,
                              void* d_out, int out_size, void* d_ws, size_t ws_size,
                              hipStream_t stream) {
    const int*   ei    = (const int*)d_in[1];
    const int*   batch = (const int*)d_in[3];
    const float* x     = (const float*)d_in[0];
    const float* ew    = (const float*)d_in[2];
    const float* Win   = (const float*)d_in[4];
    const float* bin   = (const float*)d_in[5];
    const float* W1    = (const float*)d_in[6];
    const float* b1    = (const float*)d_in[7];
    const float* W2    = (const float*)d_in[8];
    const float* b2    = (const float*)d_in[9];
    const float* Wmu   = (const float*)d_in[10];
    const float* bmu   = (const float*)d_in[11];
    const float* Wlv   = (const float*)d_in[12];
    const float* blv   = (const float*)d_in[13];
    const float* g1    = (const float*)d_in[14];
    const float* be1   = (const float*)d_in[15];
    const float* rm1   = (const float*)d_in[16];
    const float* rv1   = (const float*)d_in[17];
    const float* g2    = (const float*)d_in[18];
    const float* be2   = (const float*)d_in[19];
    const float* rm2   = (const float*)d_in[20];
    const float* rv2   = (const float*)d_in[21];
    const float* Wa1   = (const float*)d_in[22];
    const float* ba1   = (const float*)d_in[23];
    const float* Wa2   = (const float*)d_in[24];
    const float* ba2   = (const float*)d_in[25];
    const float* Wc1   = (const float*)d_in[26];
    const float* bc1   = (const float*)d_in[27];
    const float* Wc2   = (const float*)d_in[28];
    const float* bc2   = (const float*)d_in[29];
    const float* Wc3   = (const float*)d_in[30];
    const float* bc3   = (const float*)d_in[31];
    const float* Wn1   = (const float*)d_in[32];
    const float* bn1   = (const float*)d_in[33];
    const float* Wn2   = (const float*)d_in[34];
    const float* bn2   = (const float*)d_in[35];

    float* outp = (float*)d_out;

    // workspace layout (lifetime overlays keep high-water ~53 MB, below known-good 56 MB):
    //   recP slot (14.45 MB): recP [pass1..pass2c]  ->  bufA [gemmbn..]
    //   epack slot (7.23 MB): epack [pass2b..agg16] ->  zh   [aggB<1>..]
    char* ws = (char*)d_ws;
    size_t o = 0;
    auto alloc = [&](size_t bytes) { size_t r = o; o = (o + bytes + 511) & ~((size_t)511); return r; };
    int*      flags  = (int*)     (ws + alloc(16));
    float*    dinv   = (float*)   (ws + alloc(N_NODES * 4));
    unsigned* nodeInfo=(unsigned*)(ws + alloc(N_NODES * 4));
    int*      bcnt   = (int*)     (ws + alloc(NBUCK * 4));
    int*      bcnt2  = (int*)     (ws + alloc(784 * 4));
    char*     slotA  =            (ws + alloc((size_t)NBUCK * CAPB * 8));   // 14.45 MB
    uint2*    recP   = (uint2*)   slotA;
    __half*   bufA   = (__half*)  slotA;                                    // overlay (50000*128*2 = 12.8 MB)
    char*     slotB  =            (ws + alloc((size_t)NBUCK * CAPB * 4));   // 7.23 MB
    unsigned* epack  = (unsigned*)slotB;
    __half*   zh     = (__half*)  slotB;                                    // overlay (50000*64*2 = 6.4 MB)
    uint2*    recS   = (uint2*)   (ws + alloc((size_t)784 * CAP64 * 8));    // 16.06 MB
    float*    pexp   = (float*)   (ws + alloc(N_NODES * 4));
    float*    Sd     = (float*)   (ws + alloc(N_NODES * 4));
    __half*   aggx   = (__half*)  (ws + alloc((size_t)N_NODES * 16 * 2));
    _Float16* W2sw   = (_Float16*)(ws + alloc(HF * HF * 2));
    _Float16* Wcsw   = (_Float16*)(ws + alloc(HF * HF * 2));
    _Float16* Wasw   = (_Float16*)(ws + alloc(LF * HF * 2));
    float*    Weff   = (float*)   (ws + alloc(16 * HF * 4));
    float*    beff   = (float*)   (ws + alloc(HF * 4));
    float*    bcat   = (float*)   (ws + alloc(HF * 4));
    float*    sc1    = (float*)   (ws + alloc(HF * 4));
    float*    sh1    = (float*)   (ws + alloc(HF * 4));
    float*    sc2    = (float*)   (ws + alloc(HF * 4));
    float*    sh2    = (float*)   (ws + alloc(HF * 4));
    float*    red    = (float*)   (ws + alloc(16));
    float*    gpool  = (float*)   (ws + alloc(NB * LF * 4));
    float*    zsum   = (float*)   (ws + alloc(NB * LF * 4));
    float*    cnt    = (float*)   (ws + alloc(NB * 4));
    __half*   bufB   = (__half*)  (ws + alloc((size_t)50048 * 128 * 2));    // 12.8 MB
    (void)ws_size; (void)n_in; (void)in_sizes; (void)out_size;

    const int GN = (N_NODES + 255) / 256;     // 196
    const int GP = (N_EDGES + EPB - 1) / EPB; // 782

    hipLaunchKernelGGL(init_k, dim3(GN), dim3(256), 0, stream,
                       ei, flags, bcnt, gpool, zsum, cnt, red,
                       W2sw, Wcsw, Wasw, bcat, sc1, sh1, sc2, sh2,
                       W2, Wmu, bmu, Wlv, blv, Wa1,
                       g1, be1, rm1, rv1, g2, be2, rm2, rv2);
    hipLaunchKernelGGL(weff_k, dim3(8), dim3(256), 0, stream, Win, bin, W1, b1, Weff, beff);
    hipLaunchKernelGGL(pass1_k, dim3(GP), dim3(256), 0, stream, ei, ew, bcnt, recP, flags);
    hipLaunchKernelGGL(pass2a_k, dim3(NBUCK), dim3(256), 0, stream, recP, bcnt, nodeInfo, dinv);
    hipLaunchKernelGGL(pass2b_k, dim3(NBUCK), dim3(256), 0, stream, recP, bcnt, nodeInfo, epack);
    hipLaunchKernelGGL(pass2c_k, dim3(NBUCK), dim3(256), 0, stream, recP, bcnt, recS, bcnt2);

    // encoder
    const int G16 = (N_NODES + 31) / 32;      // 1563
    const int GM  = (N_NODES + 63) / 64;      // 782
    hipLaunchKernelGGL(agg16_k, dim3(G16), dim3(256), 0, stream, x, epack, nodeInfo, dinv, aggx, Sd);
    // recP dead from here: bufA occupies its slot
    hipLaunchKernelGGL(gemmbn_k, dim3(N_NODES / 16), dim3(128), 0, stream,
                       aggx, Sd, Weff, beff, sc1, sh1, bufA);                      // h1 -> A
    hipLaunchKernelGGL(gemm128_k, dim3(GM), dim3(256), 0, stream, bufA, W2sw, b2, dinv, bufB);  // t2 -> B
    hipLaunchKernelGGL((aggB_k<0>), dim3(NB64), dim3(256), 0, stream,
                       bufB, recS, bcnt2, dinv, sc2, sh2, bufA, (__half*)nullptr, (float*)nullptr); // h2 -> A
    hipLaunchKernelGGL(gemm128_k, dim3(GM), dim3(256), 0, stream, bufA, Wcsw, bcat, dinv, bufB);  // t3 -> B
    // epack dead from here: zh occupies its slot
    hipLaunchKernelGGL((aggB_k<1>), dim3(NB64), dim3(256), 0, stream,
                       bufB, recS, bcnt2, dinv, (const float*)nullptr, (const float*)nullptr,
                       (__half*)nullptr, zh, outp);

    // attention + pooling + heads
    hipLaunchKernelGGL(att_k, dim3(GM), dim3(256), 0, stream, zh, Wasw, ba1, Wa2, ba2, pexp, red);
    hipLaunchKernelGGL(pool_k, dim3(GN), dim3(256), 0, stream, zh, pexp, batch, gpool, zsum, cnt, flags);
    hipLaunchKernelGGL(head_k, dim3(NB), dim3(128), 0, stream,
                       gpool, zsum, cnt, red, Wc1, bc1, Wc2, bc2, Wc3, bc3,
                       Wn1, bn1, Wn2, bn2, outp);
}

// Round 3
// 634.763 us; speedup vs baseline: 4.8434x; 4.8434x over previous
//
#include <hip/hip_runtime.h>
#include <hip/hip_fp16.h>

typedef unsigned short ushort_t;
typedef _Float16 h8v __attribute__((ext_vector_type(8)));
typedef float f4v __attribute__((ext_vector_type(4)));

#define N_NODES 50000
#define N_EDGES 1600000
#define NB      64
#define HF      128
#define LF      64
#define NC      6
#define EPSBN   1e-5f
#define NBUCK   196          // dst buckets of 256 nodes
#define CAPB    9216         // per-bucket padded capacity
#define EPB     2048         // edges per pass1 block
#define NWIN    7            // src windows of 8192 rows (2 MB of fp16 lin -> fits 4MB XCD L2)

// output element offsets (fp32 out confirmed in round 3)
#define OPRED_OFF 0
#define OMU_OFF   384
#define OLV_OFF   3200384
#define ONOI_OFF  6400384

__device__ __forceinline__ int clampi(int v, int lo, int hi) {
    return v < lo ? lo : (v > hi ? hi : v);
}

// ============ init: detect int width, zero counters/pools, fold BN, swizzle weights ============
__global__ void init_k(const int* ei_raw, int* flags,
                       int* bcnt, float* gpool, float* zsum, float* cnt, float* red,
                       _Float16* W2sw, _Float16* Wcsw, _Float16* Wasw,
                       float* bcat, float* sc1, float* sh1, float* sc2, float* sh2,
                       const float* W2,
                       const float* Wmu, const float* bmu, const float* Wlv, const float* blv,
                       const float* Wa1,
                       const float* g1, const float* be1, const float* rm1, const float* rv1,
                       const float* g2, const float* be2, const float* rm2, const float* rv2) {
    int i = blockIdx.x * 256 + threadIdx.x;
    if (blockIdx.x == 0) {
        __shared__ int c1s;
        if (threadIdx.x == 0) c1s = 0;
        __syncthreads();
        if (ei_raw[2 * threadIdx.x + 1] != 0) atomicAdd(&c1s, 1);
        __syncthreads();
        if (threadIdx.x == 0) flags[1] = (c1s == 0) ? 1 : 0;
    }
    if (i < NBUCK) bcnt[i] = 0;
    if (i < NB * LF) { gpool[i] = 0.f; zsum[i] = 0.f; }
    if (i < NB) cnt[i] = 0.f;
    if (i < 4) red[i] = 0.f;
    if (i < HF * HF) {
        int k = i >> 7, c = i & 127;
        int idx = ((k >> 5) * 128 + c) * 32 + (k & 31);
        W2sw[idx] = (_Float16)W2[i];
        float wc = (c < 64) ? Wmu[k * 64 + c] : Wlv[k * 64 + (c - 64)];
        Wcsw[idx] = (_Float16)wc;
    }
    if (i < LF * HF) {
        int k = i >> 7, c = i & 127;
        int idx = ((k >> 5) * 128 + c) * 32 + (k & 31);
        Wasw[idx] = (_Float16)Wa1[i];
    }
    if (i < HF) {
        bcat[i] = (i < 64) ? bmu[i] : blv[i - 64];
        float s1 = g1[i] * rsqrtf(rv1[i] + EPSBN);
        sc1[i] = s1; sh1[i] = be1[i] - rm1[i] * s1;
        float s2 = g2[i] * rsqrtf(rv2[i] + EPSBN);
        sc2[i] = s2; sh2[i] = be2[i] - rm2[i] * s2;
    }
}

// ============ fold input layer into GCN-1 linear: Weff = Win@W1, beff = bin@W1 + b1 ============
__global__ __launch_bounds__(256) void weff_k(const float* __restrict__ Win,
                                              const float* __restrict__ bin,
                                              const float* __restrict__ W1,
                                              const float* __restrict__ b1,
                                              float* __restrict__ Weff,
                                              float* __restrict__ beff) {
    int i = blockIdx.x * 256 + threadIdx.x;
    if (i < 16 * 128) {
        int k = i >> 7, c = i & 127;
        float acc = 0.f;
        for (int j = 0; j < 128; j++) acc += Win[k * 128 + j] * W1[j * 128 + c];
        Weff[i] = acc;
    }
    if (i < 128) {
        float acc = b1[i];
        for (int j = 0; j < 128; j++) acc += bin[j] * W1[j * 128 + i];
        beff[i] = acc;
    }
}

// ============ pass 1: block-local LDS counting sort + run-append to padded buckets ============
__global__ __launch_bounds__(256) void pass1_k(const int* __restrict__ ei,
                                               const float* __restrict__ ew,
                                               int* __restrict__ bcnt,
                                               uint2* __restrict__ recP,
                                               const int* __restrict__ flags) {
    __shared__ uint2 stg[EPB];
    __shared__ int lh[NBUCK];
    __shared__ int lcur[NBUCK];
    __shared__ int gb[NBUCK];
    __shared__ int loff[256];
    int tid = threadIdx.x;
    for (int i = tid; i < NBUCK; i += 256) lh[i] = 0;
    __syncthreads();
    int e0 = blockIdx.x * EPB;
    int i64 = flags[1];
    uint2 myrec[8]; int myb[8];
#pragma unroll
    for (int j = 0; j < 8; j++) {
        int e = e0 + j * 256 + tid;
        if (e < N_EDGES) {
            int di = N_EDGES + e;
            int s = clampi(ei[i64 ? 2 * e : e], 0, N_NODES - 1);
            int d = clampi(ei[i64 ? 2 * di : di], 0, N_NODES - 1);
            myrec[j] = make_uint2((unsigned)s | ((unsigned)d << 16), __float_as_uint(ew[e]));
            myb[j] = d >> 8;
            atomicAdd(&lh[myb[j]], 1);
        } else myb[j] = -1;
    }
    __syncthreads();
    loff[tid] = (tid < NBUCK) ? lh[tid] : 0;
    __syncthreads();
    for (int dth = 1; dth < 256; dth <<= 1) {
        int x = (tid >= dth) ? loff[tid - dth] : 0;
        __syncthreads();
        loff[tid] += x;
        __syncthreads();
    }
    if (tid < NBUCK) lcur[tid] = loff[tid] - lh[tid];
    __syncthreads();
#pragma unroll
    for (int j = 0; j < 8; j++) {
        if (myb[j] >= 0) {
            int p = atomicAdd(&lcur[myb[j]], 1);
            stg[p] = myrec[j];
        }
    }
    if (tid < NBUCK) {
        int c = lh[tid];
        gb[tid] = (c > 0) ? atomicAdd(&bcnt[tid], c) : 0;
    }
    __syncthreads();
    int total = N_EDGES - e0; if (total > EPB) total = EPB;
    for (int idx = tid; idx < total; idx += 256) {
        uint2 r = stg[idx];
        int b = (int)(r.x >> 24);
        int within = idx - (loff[b] - lh[b]);
        int pos = gb[b] + within;
        if (pos < CAPB) recP[b * CAPB + pos] = r;
    }
}

// ============ pass 2 (merged 2a+2b): hist per (dst,src-window) + degree -> nodeInfo, dinv, ============
// window-segment table segs[n] (8x u16 cumulative ends), then scatter packed 4B records into
// epack sorted by (dst, src>>13).  nodeInfo[n] = (b*CAPB + excl) | (cnt << 21).
__global__ __launch_bounds__(256) void pass2_k(const uint2* __restrict__ recP,
                                               const int* __restrict__ bcnt,
                                               unsigned* __restrict__ nodeInfo,
                                               float* __restrict__ dinv,
                                               unsigned* __restrict__ epack,
                                               uint4* __restrict__ segs) {
    __shared__ int cw[256 * 8];    // per-(dst-local, window) count, then scatter cursor
    __shared__ float degs[256];
    __shared__ int off[256];
    int b = blockIdx.x, t = threadIdx.x;
    for (int i = t; i < 2048; i += 256) cw[i] = 0;
    degs[t] = 0.f;
    __syncthreads();
    int cb = bcnt[b]; if (cb > CAPB) cb = CAPB;
    int n0 = b * CAPB;
    for (int i = t; i < cb; i += 256) {
        uint2 r = recP[n0 + i];
        int dl = (r.x >> 16) & 255, s = (int)(r.x & 0xFFFFu);
        atomicAdd(&cw[dl * 8 + (s >> 13)], 1);
        atomicAdd(&degs[dl], __uint_as_float(r.y));
    }
    __syncthreads();
    int c[8]; int v = 0;
#pragma unroll
    for (int w = 0; w < 8; w++) { c[w] = cw[t * 8 + w]; v += c[w]; }
    off[t] = v;
    __syncthreads();
    for (int dth = 1; dth < 256; dth <<= 1) {
        int x = (t >= dth) ? off[t - dth] : 0;
        __syncthreads();
        off[t] += x;
        __syncthreads();
    }
    int excl = off[t] - v;
    int run = excl;
    ushort_t se[8];
#pragma unroll
    for (int w = 0; w < 8; w++) { cw[t * 8 + w] = run; run += c[w]; se[w] = (ushort_t)(run - excl); }
    int n = (b << 8) + t;
    if (n < N_NODES) {
        int cv = v > 2047 ? 2047 : v;
        nodeInfo[n] = (unsigned)(n0 + excl) | ((unsigned)cv << 21);
        dinv[n] = rsqrtf(1.f + degs[t]);
        uint4 sv;
        sv.x = (unsigned)se[0] | ((unsigned)se[1] << 16);
        sv.y = (unsigned)se[2] | ((unsigned)se[3] << 16);
        sv.z = (unsigned)se[4] | ((unsigned)se[5] << 16);
        sv.w = (unsigned)se[6] | ((unsigned)se[7] << 16);
        segs[n] = sv;
    }
    __syncthreads();
    for (int i = t; i < cb; i += 256) {
        uint2 r = recP[n0 + i];
        int dl = (r.x >> 16) & 255, s = (int)(r.x & 0xFFFFu);
        int p = atomicAdd(&cw[dl * 8 + (s >> 13)], 1);
        __half hw = __float2half(__uint_as_float(r.y));
        epack[n0 + p] = (unsigned)s | ((unsigned)__half_as_ushort(hw) << 16);
    }
}

// ============ agg16: 16-dim aggregation of raw x (pre-linear), 8 lanes per node ============
// aggx[d] = dinv_d * (sum_e ew*dinv_s*x[s] + dinv_d*x[d]);  Sd = dinv_d*(sum ew*dinv_s + dinv_d)
__global__ __launch_bounds__(256) void agg16_k(const float* __restrict__ x,
                                               const unsigned* __restrict__ epack,
                                               const unsigned* __restrict__ nodeInfo,
                                               const float* __restrict__ dinv,
                                               __half* __restrict__ aggx,
                                               float* __restrict__ Sd) {
    int tid = threadIdx.x;
    int n = blockIdx.x * 32 + (tid >> 3);
    if (n >= N_NODES) return;
    int f = tid & 7;
    unsigned info = nodeInfo[n];
    int e0 = (int)(info & 0x1FFFFFu);
    int e1 = e0 + (int)(info >> 21);
    float dv = dinv[n];
    float2 xs = *(const float2*)(x + n * 16 + f * 2);
    float ax = dv * xs.x, ay = dv * xs.y;
    float ss = dv;
    int e = e0;
    for (; e + 8 <= e1; e += 8) {
        unsigned r[8];
#pragma unroll
        for (int j = 0; j < 8; j++) r[j] = epack[e + j];
        float2 v[8]; float w[8];
#pragma unroll
        for (int j = 0; j < 8; j++) {
            int s = (int)(r[j] & 0xFFFFu);
            w[j] = __half2float(__ushort_as_half((ushort_t)(r[j] >> 16))) * dinv[s];
            v[j] = *(const float2*)(x + s * 16 + f * 2);
        }
#pragma unroll
        for (int j = 0; j < 8; j++) {
            ax += w[j] * v[j].x; ay += w[j] * v[j].y; ss += w[j];
        }
    }
    for (; e < e1; e++) {
        unsigned r = epack[e];
        int s = (int)(r & 0xFFFFu);
        float w = __half2float(__ushort_as_half((ushort_t)(r >> 16))) * dinv[s];
        float2 v = *(const float2*)(x + s * 16 + f * 2);
        ax += w * v.x; ay += w * v.y; ss += w;
    }
    *(__half2*)(aggx + n * 16 + 2 * f) = __floats2half2_rn(ax * dv, ay * dv);
    if (f == 0) Sd[n] = dv * ss;
}

// ============ layer-1 linear + BN + ReLU: h1 = relu(sc1*(aggx@Weff + Sd*beff) + sh1) ============
__global__ __launch_bounds__(128) void gemmbn_k(const __half* __restrict__ aggx,
                                                const float* __restrict__ Sd,
                                                const float* __restrict__ Weff,
                                                const float* __restrict__ beff,
                                                const float* __restrict__ sc1,
                                                const float* __restrict__ sh1,
                                                __half* __restrict__ out) {
    __shared__ float xl[16 * 16];
    __shared__ float sdl[16];
    int tid = threadIdx.x;
    int row0 = blockIdx.x * 16;
    if (tid < 64) {
        int r = tid >> 2, k4 = tid & 3;
        int row = row0 + r;
        float4 v4 = make_float4(0.f, 0.f, 0.f, 0.f);
        if (row < N_NODES) {
            __half2 h0 = *(const __half2*)(aggx + row * 16 + k4 * 4);
            __half2 h1 = *(const __half2*)(aggx + row * 16 + k4 * 4 + 2);
            float2 f0 = __half22float2(h0), f1 = __half22float2(h1);
            v4 = make_float4(f0.x, f0.y, f1.x, f1.y);
        }
        *(float4*)(xl + r * 16 + k4 * 4) = v4;
    }
    if (tid < 16) {
        int row = row0 + tid;
        sdl[tid] = (row < N_NODES) ? Sd[row] : 0.f;
    }
    float wv[16];
#pragma unroll
    for (int k = 0; k < 16; k++) wv[k] = Weff[k * 128 + tid];
    float bias = beff[tid];
    float s1 = sc1[tid], h1v = sh1[tid];
    __syncthreads();
    for (int r = 0; r < 16; r++) {
        float acc = sdl[r] * bias;
#pragma unroll
        for (int k = 0; k < 16; k++) acc += xl[r * 16 + k] * wv[k];
        int row = row0 + r;
        if (row < N_NODES) {
            float o = fmaxf(acc * s1 + h1v, 0.f);
            out[row * 128 + tid] = __float2half(o);
        }
    }
}

// ============ MFMA GEMM: in(fp16)[N,128] @ Wsw + b, epilogue scales rows by dinv -> fp16 ============
__global__ __launch_bounds__(256) void gemm128_k(const __half* __restrict__ in,
                                                 const _Float16* __restrict__ Wsw,
                                                 const float* __restrict__ b,
                                                 const float* __restrict__ dinv,
                                                 __half* __restrict__ out) {
    int l = threadIdx.x & 63, w = threadIdx.x >> 6;
    int row0 = blockIdx.x * 64 + w * 16;
    int m = l & 15, q = l >> 4;
    int row = row0 + m;
    bool rok = row < N_NODES;
    const h8v* inp = (const h8v*)in;
    const h8v* wp = (const h8v*)Wsw;
    h8v az = {0, 0, 0, 0, 0, 0, 0, 0};
    h8v a[4];
#pragma unroll
    for (int kb = 0; kb < 4; kb++)
        a[kb] = rok ? inp[(row * 128 + kb * 32 + q * 8) >> 3] : az;
    float dv4[4];
#pragma unroll
    for (int r = 0; r < 4; r++) {
        int orow = row0 + q * 4 + r;
        dv4[r] = (orow < N_NODES) ? dinv[orow] : 0.f;
    }
#pragma unroll
    for (int ct = 0; ct < 8; ct++) {
        f4v acc = {0.f, 0.f, 0.f, 0.f};
#pragma unroll
        for (int kb = 0; kb < 4; kb++) {
            h8v bf = wp[((kb * 128 + ct * 16 + m) * 32 + q * 8) >> 3];
            acc = __builtin_amdgcn_mfma_f32_16x16x32_f16(a[kb], bf, acc, 0, 0, 0);
        }
        int col = ct * 16 + m;
        float bias = b[col];
#pragma unroll
        for (int r = 0; r < 4; r++) {
            int orow = row0 + q * 4 + r;
            if (orow < N_NODES) out[orow * 128 + col] = __float2half((acc[r] + bias) * dv4[r]);
        }
    }
}

// ============ windowed pull aggregation: resident grid, chip-wide src-window sweep ============
// 782 blocks (~3/CU, all co-resident), each owns 64 dst nodes: 4 groups of 64 lanes x 16 nodes.
// Register acc[16] (static-indexed). Pass p gathers only edges with src in window p (2MB lin
// slice) -> concurrent blocks share an L2-resident window. Worst case (drift) ~= old agg_k.
// MODE 0: + BN+ReLU -> outH fp16.  MODE 1: mu/logvar fp32 outs + zh fp16.
template <int MODE>
__global__ __launch_bounds__(256) void aggW_k(const __half* __restrict__ lin,
                                              const unsigned* __restrict__ epack,
                                              const unsigned* __restrict__ nodeInfo,
                                              const uint4* __restrict__ segs,
                                              const float* __restrict__ dinv,
                                              const float* __restrict__ sc,
                                              const float* __restrict__ sh,
                                              __half* __restrict__ outH,
                                              __half* __restrict__ zh,
                                              float* __restrict__ outp) {
    __shared__ unsigned infoL[64];
    __shared__ ushort_t segL[64 * 8];
    int t = threadIdx.x, l = t & 63, g = t >> 6;
    int nb0 = blockIdx.x * 64;
    if (t < 64) {
        int n = nb0 + t;
        infoL[t] = (n < N_NODES) ? nodeInfo[n] : 0u;
        uint4 sv = (n < N_NODES) ? segs[n] : make_uint4(0, 0, 0, 0);
        segL[t * 8 + 0] = (ushort_t)(sv.x & 0xFFFFu); segL[t * 8 + 1] = (ushort_t)(sv.x >> 16);
        segL[t * 8 + 2] = (ushort_t)(sv.y & 0xFFFFu); segL[t * 8 + 3] = (ushort_t)(sv.y >> 16);
        segL[t * 8 + 4] = (ushort_t)(sv.z & 0xFFFFu); segL[t * 8 + 5] = (ushort_t)(sv.z >> 16);
        segL[t * 8 + 6] = (ushort_t)(sv.w & 0xFFFFu); segL[t * 8 + 7] = (ushort_t)(sv.w >> 16);
    }
    __syncthreads();
    const __half2* linv = (const __half2*)lin;
    int n0 = nb0 + g * 16;
    float2 acc[16];
#pragma unroll
    for (int nd = 0; nd < 16; nd++) {
        int n = n0 + nd;
        acc[nd] = (n < N_NODES) ? __half22float2(linv[n * 64 + l]) : make_float2(0.f, 0.f);
    }
    for (int p = 0; p < NWIN; p++) {
#pragma unroll
        for (int nd = 0; nd < 16; nd++) {
            int n = n0 + nd;
            if (n >= N_NODES) continue;
            int li = g * 16 + nd;
            int e0 = (int)(infoL[li] & 0x1FFFFFu);
            int a = p ? (int)segL[li * 8 + p - 1] : 0;
            int bq = (int)segL[li * 8 + p];
            int e = e0 + a, ee = e0 + bq;
            float ax = acc[nd].x, ay = acc[nd].y;
            for (; e + 4 <= ee; e += 4) {
                unsigned r0 = epack[e], r1 = epack[e + 1], r2 = epack[e + 2], r3 = epack[e + 3];
                __half2 v0 = linv[(int)(r0 & 0xFFFFu) * 64 + l];
                __half2 v1 = linv[(int)(r1 & 0xFFFFu) * 64 + l];
                __half2 v2 = linv[(int)(r2 & 0xFFFFu) * 64 + l];
                __half2 v3 = linv[(int)(r3 & 0xFFFFu) * 64 + l];
                float w0 = __half2float(__ushort_as_half((ushort_t)(r0 >> 16)));
                float w1 = __half2float(__ushort_as_half((ushort_t)(r1 >> 16)));
                float w2 = __half2float(__ushort_as_half((ushort_t)(r2 >> 16)));
                float w3 = __half2float(__ushort_as_half((ushort_t)(r3 >> 16)));
                float2 f0 = __half22float2(v0), f1 = __half22float2(v1);
                float2 f2 = __half22float2(v2), f3 = __half22float2(v3);
                ax += w0 * f0.x + w1 * f1.x + w2 * f2.x + w3 * f3.x;
                ay += w0 * f0.y + w1 * f1.y + w2 * f2.y + w3 * f3.y;
            }
            for (; e < ee; e++) {
                unsigned r = epack[e];
                float w = __half2float(__ushort_as_half((ushort_t)(r >> 16)));
                float2 f = __half22float2(linv[(int)(r & 0xFFFFu) * 64 + l]);
                ax += w * f.x; ay += w * f.y;
            }
            acc[nd].x = ax; acc[nd].y = ay;
        }
    }
#pragma unroll
    for (int nd = 0; nd < 16; nd++) {
        int n = n0 + nd;
        if (n >= N_NODES) continue;
        float dv = dinv[n];
        float ax = acc[nd].x * dv, ay = acc[nd].y * dv;
        if (MODE == 0) {
            float2 s2 = *(const float2*)(sc + 2 * l);
            float2 h2 = *(const float2*)(sh + 2 * l);
            float o0 = fmaxf(ax * s2.x + h2.x, 0.f);
            float o1 = fmaxf(ay * s2.y + h2.y, 0.f);
            *(__half2*)(outH + n * 128 + 2 * l) = __floats2half2_rn(o0, o1);
        } else {
            if (l < 32) {
                *(float2*)(outp + OMU_OFF + n * 64 + 2 * l) = make_float2(ax, ay);
                ((__half2*)zh)[n * 32 + l] = __floats2half2_rn(ax, ay);
            } else {
                *(float2*)(outp + OLV_OFF + n * 64 + (2 * l - 64)) = make_float2(ax, ay);
            }
        }
    }
}

// ============ attention via MFMA: p = exp(tanh(zh @ Wa1 + ba1) @ Wa2 + ba2) ============
__global__ __launch_bounds__(256) void att_k(const __half* __restrict__ zh,
                                             const _Float16* __restrict__ Wasw,
                                             const float* __restrict__ ba1,
                                             const float* __restrict__ Wa2,
                                             const float* __restrict__ ba2,
                                             float* __restrict__ p, float* __restrict__ red) {
    __shared__ float rsum[4];
    int l = threadIdx.x & 63, w = threadIdx.x >> 6;
    int row0 = blockIdx.x * 64 + w * 16;
    int m = l & 15, q = l >> 4;
    int row = row0 + m;
    bool rok = row < N_NODES;
    const h8v* zp = (const h8v*)zh;
    const h8v* wp = (const h8v*)Wasw;
    h8v az = {0, 0, 0, 0, 0, 0, 0, 0};
    h8v a[2];
#pragma unroll
    for (int kb = 0; kb < 2; kb++)
        a[kb] = rok ? zp[(row * 64 + kb * 32 + q * 8) >> 3] : az;
    float ysum[4] = {0.f, 0.f, 0.f, 0.f};
#pragma unroll
    for (int ct = 0; ct < 8; ct++) {
        f4v acc = {0.f, 0.f, 0.f, 0.f};
#pragma unroll
        for (int kb = 0; kb < 2; kb++) {
            h8v bf = wp[((kb * 128 + ct * 16 + m) * 32 + q * 8) >> 3];
            acc = __builtin_amdgcn_mfma_f32_16x16x32_f16(a[kb], bf, acc, 0, 0, 0);
        }
        int col = ct * 16 + m;
        float bb = ba1[col], wa2 = Wa2[col];
#pragma unroll
        for (int r = 0; r < 4; r++) ysum[r] += tanhf(acc[r] + bb) * wa2;
    }
#pragma unroll
    for (int off = 1; off < 16; off <<= 1) {
#pragma unroll
        for (int r = 0; r < 4; r++) ysum[r] += __shfl_xor(ysum[r], off, 64);
    }
    float wsum = 0.f;
    if (m == 0) {
        float ba2v = ba2[0];
#pragma unroll
        for (int r = 0; r < 4; r++) {
            int orow = row0 + q * 4 + r;
            if (orow < N_NODES) {
                float pe = expf(ysum[r] + ba2v);
                p[orow] = pe;
                wsum += pe;
            }
        }
    }
    wsum += __shfl_xor(wsum, 16, 64);
    wsum += __shfl_xor(wsum, 32, 64);
    if (l == 0) rsum[w] = wsum;
    __syncthreads();
    if (threadIdx.x == 0)
        atomicAdd(&red[1], rsum[0] + rsum[1] + rsum[2] + rsum[3]);
}

// ============ pooling (4 groups of 64 per block) ============
__global__ __launch_bounds__(256) void pool_k(const __half* __restrict__ zh,
                                              const float* __restrict__ p,
                                              const int* __restrict__ batch,
                                              float* gpool, float* zsum, float* cnt,
                                              const int* __restrict__ flags) {
    int l = threadIdx.x & 63, g = threadIdx.x >> 6;
    int i64 = flags[1];
    int nstart = blockIdx.x * 256 + g * 64;
    float ag = 0.f, az = 0.f, c = 0.f;
    int cur = -1;
    for (int i = 0; i < 64; i++) {
        int n = nstart + i;
        if (n >= N_NODES) break;
        int b = clampi(batch[i64 ? 2 * n : n], 0, NB - 1);
        if (b != cur) {
            if (cur >= 0) {
                atomicAdd(&gpool[cur * 64 + l], ag);
                atomicAdd(&zsum[cur * 64 + l], az);
                if (l == 0) atomicAdd(&cnt[cur], c);
            }
            cur = b; ag = 0.f; az = 0.f; c = 0.f;
        }
        float pe = p[n];
        float zv = __half2float(zh[n * 64 + l]);
        ag += pe * zv; az += zv; c += 1.f;
    }
    if (cur >= 0) {
        atomicAdd(&gpool[cur * 64 + l], ag);
        atomicAdd(&zsum[cur * 64 + l], az);
        if (l == 0) atomicAdd(&cnt[cur], c);
    }
}

// ============ per-graph heads ============
__global__ __launch_bounds__(128) void head_k(const float* __restrict__ gpool,
                                              const float* __restrict__ zsum,
                                              const float* __restrict__ cnt,
                                              const float* __restrict__ red,
                                              const float* Wc1, const float* bc1,
                                              const float* Wc2, const float* bc2,
                                              const float* Wc3, const float* bc3,
                                              const float* Wn1, const float* bn1,
                                              const float* Wn2, const float* bn2,
                                              float* __restrict__ outp) {
    __shared__ float gsh[64], zm[64], p1[128], p2[64], n1[64];
    int b = blockIdx.x, t = threadIdx.x;
    float S = red[1];
    if (t < 64) {
        gsh[t] = gpool[b * 64 + t] / S;
        zm[t] = zsum[b * 64 + t] / fmaxf(cnt[b], 1.f);
    }
    __syncthreads();
    {
        float acc = bc1[t];
        for (int k = 0; k < 64; k++) acc += gsh[k] * Wc1[k * 128 + t];
        p1[t] = fmaxf(acc, 0.f);
    }
    __syncthreads();
    if (t < 64) {
        float acc = bc2[t];
        for (int k = 0; k < 128; k++) acc += p1[k] * Wc2[k * 64 + t];
        p2[t] = fmaxf(acc, 0.f);
    } else {
        int tt = t - 64;
        float acc = bn1[tt];
        for (int k = 0; k < 64; k++) acc += zm[k] * Wn1[k * 64 + tt];
        n1[tt] = fmaxf(acc, 0.f);
    }
    __syncthreads();
    if (t < NC) {
        float acc = bc3[t];
        for (int k = 0; k < 64; k++) acc += p2[k] * Wc3[k * 6 + t];
        outp[OPRED_OFF + b * 6 + t] = acc;
    }
    if (t == 64) {
        float acc = bn2[0];
        for (int k = 0; k < 64; k++) acc += n1[k] * Wn2[k];
        outp[ONOI_OFF + b] = 1.f / (1.f + expf(-acc));
    }
}

extern "C" void kernel_launch(void* const* d_in, const int* in_sizes, int n_in,
                              void* d_out, int out_size, void* d_ws, size_t ws_size,
                              hipStream_t stream) {
    const int*   ei    = (const int*)d_in[1];
    const int*   batch = (const int*)d_in[3];
    const float* x     = (const float*)d_in[0];
    const float* ew    = (const float*)d_in[2];
    const float* Win   = (const float*)d_in[4];
    const float* bin   = (const float*)d_in[5];
    const float* W1    = (const float*)d_in[6];
    const float* b1    = (const float*)d_in[7];
    const float* W2    = (const float*)d_in[8];
    const float* b2    = (const float*)d_in[9];
    const float* Wmu   = (const float*)d_in[10];
    const float* bmu   = (const float*)d_in[11];
    const float* Wlv   = (const float*)d_in[12];
    const float* blv   = (const float*)d_in[13];
    const float* g1    = (const float*)d_in[14];
    const float* be1   = (const float*)d_in[15];
    const float* rm1   = (const float*)d_in[16];
    const float* rv1   = (const float*)d_in[17];
    const float* g2    = (const float*)d_in[18];
    const float* be2   = (const float*)d_in[19];
    const float* rm2   = (const float*)d_in[20];
    const float* rv2   = (const float*)d_in[21];
    const float* Wa1   = (const float*)d_in[22];
    const float* ba1   = (const float*)d_in[23];
    const float* Wa2   = (const float*)d_in[24];
    const float* ba2   = (const float*)d_in[25];
    const float* Wc1   = (const float*)d_in[26];
    const float* bc1   = (const float*)d_in[27];
    const float* Wc2   = (const float*)d_in[28];
    const float* bc2   = (const float*)d_in[29];
    const float* Wc3   = (const float*)d_in[30];
    const float* bc3   = (const float*)d_in[31];
    const float* Wn1   = (const float*)d_in[32];
    const float* bn1   = (const float*)d_in[33];
    const float* Wn2   = (const float*)d_in[34];
    const float* bn2   = (const float*)d_in[35];

    float* outp = (float*)d_out;

    // workspace layout — identical to the 438µs-verified layout + segs (0.8 MB); total ~56.8 MB
    char* ws = (char*)d_ws;
    size_t o = 0;
    auto alloc = [&](size_t bytes) { size_t r = o; o = (o + bytes + 511) & ~((size_t)511); return r; };
    int*      flags  = (int*)     (ws + alloc(16));
    float*    dinv   = (float*)   (ws + alloc(N_NODES * 4));
    unsigned* nodeInfo=(unsigned*)(ws + alloc(N_NODES * 4));
    int*      bcnt   = (int*)     (ws + alloc(NBUCK * 4));
    uint2*    recP   = (uint2*)   (ws + alloc((size_t)NBUCK * CAPB * 8));   // 14.5 MB
    unsigned* epack  = (unsigned*)(ws + alloc((size_t)NBUCK * CAPB * 4));   // 7.2 MB
    float*    pexp   = (float*)   (ws + alloc(N_NODES * 4));
    float*    Sd     = (float*)   (ws + alloc(N_NODES * 4));
    __half*   aggx   = (__half*)  (ws + alloc((size_t)N_NODES * 16 * 2));
    _Float16* W2sw   = (_Float16*)(ws + alloc(HF * HF * 2));
    _Float16* Wcsw   = (_Float16*)(ws + alloc(HF * HF * 2));
    _Float16* Wasw   = (_Float16*)(ws + alloc(LF * HF * 2));
    float*    Weff   = (float*)   (ws + alloc(16 * HF * 4));
    float*    beff   = (float*)   (ws + alloc(HF * 4));
    float*    bcat   = (float*)   (ws + alloc(HF * 4));
    float*    sc1    = (float*)   (ws + alloc(HF * 4));
    float*    sh1    = (float*)   (ws + alloc(HF * 4));
    float*    sc2    = (float*)   (ws + alloc(HF * 4));
    float*    sh2    = (float*)   (ws + alloc(HF * 4));
    float*    red    = (float*)   (ws + alloc(16));
    float*    gpool  = (float*)   (ws + alloc(NB * LF * 4));
    float*    zsum   = (float*)   (ws + alloc(NB * LF * 4));
    float*    cnt    = (float*)   (ws + alloc(NB * 4));
    __half*   bufA   = (__half*)  (ws + alloc((size_t)50048 * 128 * 2));
    __half*   bufB   = (__half*)  (ws + alloc((size_t)50048 * 128 * 2));
    __half*   zh     = (__half*)  (ws + alloc((size_t)50048 * 64 * 2));
    uint4*    segs   = (uint4*)   (ws + alloc((size_t)50048 * 16));         // 0.8 MB
    (void)ws_size; (void)n_in; (void)in_sizes; (void)out_size;

    const int GN = (N_NODES + 255) / 256;     // 196
    const int GP = (N_EDGES + EPB - 1) / EPB; // 782

    hipLaunchKernelGGL(init_k, dim3(GN), dim3(256), 0, stream,
                       ei, flags, bcnt, gpool, zsum, cnt, red,
                       W2sw, Wcsw, Wasw, bcat, sc1, sh1, sc2, sh2,
                       W2, Wmu, bmu, Wlv, blv, Wa1,
                       g1, be1, rm1, rv1, g2, be2, rm2, rv2);
    hipLaunchKernelGGL(weff_k, dim3(8), dim3(256), 0, stream, Win, bin, W1, b1, Weff, beff);
    hipLaunchKernelGGL(pass1_k, dim3(GP), dim3(256), 0, stream, ei, ew, bcnt, recP, flags);
    hipLaunchKernelGGL(pass2_k, dim3(NBUCK), dim3(256), 0, stream,
                       recP, bcnt, nodeInfo, dinv, epack, segs);

    // encoder
    const int G16 = (N_NODES + 31) / 32;      // 1563
    const int GM  = (N_NODES + 63) / 64;      // 782
    const int GW  = 782;                      // aggW: 64 nodes/block, fully resident
    hipLaunchKernelGGL(agg16_k, dim3(G16), dim3(256), 0, stream, x, epack, nodeInfo, dinv, aggx, Sd);
    hipLaunchKernelGGL(gemmbn_k, dim3(N_NODES / 16), dim3(128), 0, stream,
                       aggx, Sd, Weff, beff, sc1, sh1, bufA);                      // h1 -> A
    hipLaunchKernelGGL(gemm128_k, dim3(GM), dim3(256), 0, stream, bufA, W2sw, b2, dinv, bufB);  // t2 -> B
    hipLaunchKernelGGL((aggW_k<0>), dim3(GW), dim3(256), 0, stream,
                       bufB, epack, nodeInfo, segs, dinv, sc2, sh2,
                       bufA, (__half*)nullptr, (float*)nullptr);                   // h2 -> A
    hipLaunchKernelGGL(gemm128_k, dim3(GM), dim3(256), 0, stream, bufA, Wcsw, bcat, dinv, bufB);  // t3 -> B
    hipLaunchKernelGGL((aggW_k<1>), dim3(GW), dim3(256), 0, stream,
                       bufB, epack, nodeInfo, segs, dinv, (const float*)nullptr, (const float*)nullptr,
                       (__half*)nullptr, zh, outp);

    // attention + pooling + heads
    hipLaunchKernelGGL(att_k, dim3(GM), dim3(256), 0, stream, zh, Wasw, ba1, Wa2, ba2, pexp, red);
    hipLaunchKernelGGL(pool_k, dim3(GN), dim3(256), 0, stream, zh, pexp, batch, gpool, zsum, cnt, flags);
    hipLaunchKernelGGL(head_k, dim3(NB), dim3(128), 0, stream,
                       gpool, zsum, cnt, red, Wc1, bc1, Wc2, bc2, Wc3, bc3,
                       Wn1, bn1, Wn2, bn2, outp);
}

// Round 4
// 460.201 us; speedup vs baseline: 6.6806x; 1.3793x over previous
//
#include <hip/hip_runtime.h>
#include <hip/hip_fp16.h>

typedef unsigned short ushort_t;
typedef _Float16 h8v __attribute__((ext_vector_type(8)));
typedef float f4v __attribute__((ext_vector_type(4)));

#define N_NODES 50000
#define N_EDGES 1600000
#define NB      64
#define HF      128
#define LF      64
#define NC      6
#define EPSBN   1e-5f
#define NBUCK   196          // dst buckets of 256 nodes
#define CAPB    9216         // per-bucket padded capacity
#define EPB     2048         // edges per pass1 block
#define GRES    1250         // resident grid for aggR: ~5 blocks/CU, 10 groups each

// output element offsets (fp32 out confirmed in round 3)
#define OPRED_OFF 0
#define OMU_OFF   384
#define OLV_OFF   3200384
#define ONOI_OFF  6400384

__device__ __forceinline__ int clampi(int v, int lo, int hi) {
    return v < lo ? lo : (v > hi ? hi : v);
}

// ============ init: detect int width, zero counters/pools, fold BN, swizzle weights ============
__global__ void init_k(const int* ei_raw, int* flags,
                       int* bcnt, float* gpool, float* zsum, float* cnt, float* red,
                       _Float16* W2sw, _Float16* Wcsw, _Float16* Wasw,
                       float* bcat, float* sc1, float* sh1, float* sc2, float* sh2,
                       const float* W2,
                       const float* Wmu, const float* bmu, const float* Wlv, const float* blv,
                       const float* Wa1,
                       const float* g1, const float* be1, const float* rm1, const float* rv1,
                       const float* g2, const float* be2, const float* rm2, const float* rv2) {
    int i = blockIdx.x * 256 + threadIdx.x;
    if (blockIdx.x == 0) {
        __shared__ int c1s;
        if (threadIdx.x == 0) c1s = 0;
        __syncthreads();
        if (ei_raw[2 * threadIdx.x + 1] != 0) atomicAdd(&c1s, 1);
        __syncthreads();
        if (threadIdx.x == 0) flags[1] = (c1s == 0) ? 1 : 0;
    }
    if (i < NBUCK) bcnt[i] = 0;
    if (i < NB * LF) { gpool[i] = 0.f; zsum[i] = 0.f; }
    if (i < NB) cnt[i] = 0.f;
    if (i < 4) red[i] = 0.f;
    if (i < HF * HF) {
        int k = i >> 7, c = i & 127;
        int idx = ((k >> 5) * 128 + c) * 32 + (k & 31);
        W2sw[idx] = (_Float16)W2[i];
        float wc = (c < 64) ? Wmu[k * 64 + c] : Wlv[k * 64 + (c - 64)];
        Wcsw[idx] = (_Float16)wc;
    }
    if (i < LF * HF) {
        int k = i >> 7, c = i & 127;
        int idx = ((k >> 5) * 128 + c) * 32 + (k & 31);
        Wasw[idx] = (_Float16)Wa1[i];
    }
    if (i < HF) {
        bcat[i] = (i < 64) ? bmu[i] : blv[i - 64];
        float s1 = g1[i] * rsqrtf(rv1[i] + EPSBN);
        sc1[i] = s1; sh1[i] = be1[i] - rm1[i] * s1;
        float s2 = g2[i] * rsqrtf(rv2[i] + EPSBN);
        sc2[i] = s2; sh2[i] = be2[i] - rm2[i] * s2;
    }
}

// ============ fold input layer into GCN-1 linear: Weff = Win@W1, beff = bin@W1 + b1 ============
__global__ __launch_bounds__(256) void weff_k(const float* __restrict__ Win,
                                              const float* __restrict__ bin,
                                              const float* __restrict__ W1,
                                              const float* __restrict__ b1,
                                              float* __restrict__ Weff,
                                              float* __restrict__ beff) {
    int i = blockIdx.x * 256 + threadIdx.x;
    if (i < 16 * 128) {
        int k = i >> 7, c = i & 127;
        float acc = 0.f;
        for (int j = 0; j < 128; j++) acc += Win[k * 128 + j] * W1[j * 128 + c];
        Weff[i] = acc;
    }
    if (i < 128) {
        float acc = b1[i];
        for (int j = 0; j < 128; j++) acc += bin[j] * W1[j * 128 + i];
        beff[i] = acc;
    }
}

// ============ pass 1: block-local LDS counting sort + run-append to padded buckets ============
__global__ __launch_bounds__(256) void pass1_k(const int* __restrict__ ei,
                                               const float* __restrict__ ew,
                                               int* __restrict__ bcnt,
                                               uint2* __restrict__ recP,
                                               const int* __restrict__ flags) {
    __shared__ uint2 stg[EPB];
    __shared__ int lh[NBUCK];
    __shared__ int lcur[NBUCK];
    __shared__ int gb[NBUCK];
    __shared__ int loff[256];
    int tid = threadIdx.x;
    for (int i = tid; i < NBUCK; i += 256) lh[i] = 0;
    __syncthreads();
    int e0 = blockIdx.x * EPB;
    int i64 = flags[1];
    uint2 myrec[8]; int myb[8];
#pragma unroll
    for (int j = 0; j < 8; j++) {
        int e = e0 + j * 256 + tid;
        if (e < N_EDGES) {
            int di = N_EDGES + e;
            int s = clampi(ei[i64 ? 2 * e : e], 0, N_NODES - 1);
            int d = clampi(ei[i64 ? 2 * di : di], 0, N_NODES - 1);
            myrec[j] = make_uint2((unsigned)s | ((unsigned)d << 16), __float_as_uint(ew[e]));
            myb[j] = d >> 8;
            atomicAdd(&lh[myb[j]], 1);
        } else myb[j] = -1;
    }
    __syncthreads();
    loff[tid] = (tid < NBUCK) ? lh[tid] : 0;
    __syncthreads();
    for (int dth = 1; dth < 256; dth <<= 1) {
        int x = (tid >= dth) ? loff[tid - dth] : 0;
        __syncthreads();
        loff[tid] += x;
        __syncthreads();
    }
    if (tid < NBUCK) lcur[tid] = loff[tid] - lh[tid];
    __syncthreads();
#pragma unroll
    for (int j = 0; j < 8; j++) {
        if (myb[j] >= 0) {
            int p = atomicAdd(&lcur[myb[j]], 1);
            stg[p] = myrec[j];
        }
    }
    if (tid < NBUCK) {
        int c = lh[tid];
        gb[tid] = (c > 0) ? atomicAdd(&bcnt[tid], c) : 0;
    }
    __syncthreads();
    int total = N_EDGES - e0; if (total > EPB) total = EPB;
    for (int idx = tid; idx < total; idx += 256) {
        uint2 r = stg[idx];
        int b = (int)(r.x >> 24);
        int within = idx - (loff[b] - lh[b]);
        int pos = gb[b] + within;
        if (pos < CAPB) recP[b * CAPB + pos] = r;
    }
}

// ============ pass 2 (merged 2a+2b): hist per (dst,src-window) + degree -> nodeInfo, dinv, ============
// then scatter packed 4B records into epack sorted by (dst, src>>13).
// nodeInfo[n] = (b*CAPB + excl) | (cnt << 21).  Window-sorted lists make aggR's linear walk
// an implicit src-window sweep (L2 locality), with zero control-flow overhead.
__global__ __launch_bounds__(256) void pass2_k(const uint2* __restrict__ recP,
                                               const int* __restrict__ bcnt,
                                               unsigned* __restrict__ nodeInfo,
                                               float* __restrict__ dinv,
                                               unsigned* __restrict__ epack) {
    __shared__ int cw[256 * 8];    // per-(dst-local, window) count, then scatter cursor
    __shared__ float degs[256];
    __shared__ int off[256];
    int b = blockIdx.x, t = threadIdx.x;
    for (int i = t; i < 2048; i += 256) cw[i] = 0;
    degs[t] = 0.f;
    __syncthreads();
    int cb = bcnt[b]; if (cb > CAPB) cb = CAPB;
    int n0 = b * CAPB;
    for (int i = t; i < cb; i += 256) {
        uint2 r = recP[n0 + i];
        int dl = (r.x >> 16) & 255, s = (int)(r.x & 0xFFFFu);
        atomicAdd(&cw[dl * 8 + (s >> 13)], 1);
        atomicAdd(&degs[dl], __uint_as_float(r.y));
    }
    __syncthreads();
    int c[8]; int v = 0;
#pragma unroll
    for (int w = 0; w < 8; w++) { c[w] = cw[t * 8 + w]; v += c[w]; }
    off[t] = v;
    __syncthreads();
    for (int dth = 1; dth < 256; dth <<= 1) {
        int x = (t >= dth) ? off[t - dth] : 0;
        __syncthreads();
        off[t] += x;
        __syncthreads();
    }
    int excl = off[t] - v;
    int run = excl;
#pragma unroll
    for (int w = 0; w < 8; w++) { cw[t * 8 + w] = run; run += c[w]; }
    int n = (b << 8) + t;
    if (n < N_NODES) {
        int cv = v > 2047 ? 2047 : v;
        nodeInfo[n] = (unsigned)(n0 + excl) | ((unsigned)cv << 21);
        dinv[n] = rsqrtf(1.f + degs[t]);
    }
    __syncthreads();
    for (int i = t; i < cb; i += 256) {
        uint2 r = recP[n0 + i];
        int dl = (r.x >> 16) & 255, s = (int)(r.x & 0xFFFFu);
        int p = atomicAdd(&cw[dl * 8 + (s >> 13)], 1);
        __half hw = __float2half(__uint_as_float(r.y));
        epack[n0 + p] = (unsigned)s | ((unsigned)__half_as_ushort(hw) << 16);
    }
}

// ============ agg16: 16-dim aggregation of raw x (pre-linear), 8 lanes per node ============
// aggx[d] = dinv_d * (sum_e ew*dinv_s*x[s] + dinv_d*x[d]);  Sd = dinv_d*(sum ew*dinv_s + dinv_d)
__global__ __launch_bounds__(256) void agg16_k(const float* __restrict__ x,
                                               const unsigned* __restrict__ epack,
                                               const unsigned* __restrict__ nodeInfo,
                                               const float* __restrict__ dinv,
                                               __half* __restrict__ aggx,
                                               float* __restrict__ Sd) {
    int tid = threadIdx.x;
    int n = blockIdx.x * 32 + (tid >> 3);
    if (n >= N_NODES) return;
    int f = tid & 7;
    unsigned info = nodeInfo[n];
    int e0 = (int)(info & 0x1FFFFFu);
    int e1 = e0 + (int)(info >> 21);
    float dv = dinv[n];
    float2 xs = *(const float2*)(x + n * 16 + f * 2);
    float ax = dv * xs.x, ay = dv * xs.y;
    float ss = dv;
    int e = e0;
    for (; e + 8 <= e1; e += 8) {
        unsigned r[8];
#pragma unroll
        for (int j = 0; j < 8; j++) r[j] = epack[e + j];
        float2 v[8]; float w[8];
#pragma unroll
        for (int j = 0; j < 8; j++) {
            int s = (int)(r[j] & 0xFFFFu);
            w[j] = __half2float(__ushort_as_half((ushort_t)(r[j] >> 16))) * dinv[s];
            v[j] = *(const float2*)(x + s * 16 + f * 2);
        }
#pragma unroll
        for (int j = 0; j < 8; j++) {
            ax += w[j] * v[j].x; ay += w[j] * v[j].y; ss += w[j];
        }
    }
    for (; e < e1; e++) {
        unsigned r = epack[e];
        int s = (int)(r & 0xFFFFu);
        float w = __half2float(__ushort_as_half((ushort_t)(r >> 16))) * dinv[s];
        float2 v = *(const float2*)(x + s * 16 + f * 2);
        ax += w * v.x; ay += w * v.y; ss += w;
    }
    *(__half2*)(aggx + n * 16 + 2 * f) = __floats2half2_rn(ax * dv, ay * dv);
    if (f == 0) Sd[n] = dv * ss;
}

// ============ layer-1 linear + BN + ReLU: h1 = relu(sc1*(aggx@Weff + Sd*beff) + sh1) ============
__global__ __launch_bounds__(128) void gemmbn_k(const __half* __restrict__ aggx,
                                                const float* __restrict__ Sd,
                                                const float* __restrict__ Weff,
                                                const float* __restrict__ beff,
                                                const float* __restrict__ sc1,
                                                const float* __restrict__ sh1,
                                                __half* __restrict__ out) {
    __shared__ float xl[16 * 16];
    __shared__ float sdl[16];
    int tid = threadIdx.x;
    int row0 = blockIdx.x * 16;
    if (tid < 64) {
        int r = tid >> 2, k4 = tid & 3;
        int row = row0 + r;
        float4 v4 = make_float4(0.f, 0.f, 0.f, 0.f);
        if (row < N_NODES) {
            __half2 h0 = *(const __half2*)(aggx + row * 16 + k4 * 4);
            __half2 h1 = *(const __half2*)(aggx + row * 16 + k4 * 4 + 2);
            float2 f0 = __half22float2(h0), f1 = __half22float2(h1);
            v4 = make_float4(f0.x, f0.y, f1.x, f1.y);
        }
        *(float4*)(xl + r * 16 + k4 * 4) = v4;
    }
    if (tid < 16) {
        int row = row0 + tid;
        sdl[tid] = (row < N_NODES) ? Sd[row] : 0.f;
    }
    float wv[16];
#pragma unroll
    for (int k = 0; k < 16; k++) wv[k] = Weff[k * 128 + tid];
    float bias = beff[tid];
    float s1 = sc1[tid], h1v = sh1[tid];
    __syncthreads();
    for (int r = 0; r < 16; r++) {
        float acc = sdl[r] * bias;
#pragma unroll
        for (int k = 0; k < 16; k++) acc += xl[r * 16 + k] * wv[k];
        int row = row0 + r;
        if (row < N_NODES) {
            float o = fmaxf(acc * s1 + h1v, 0.f);
            out[row * 128 + tid] = __float2half(o);
        }
    }
}

// ============ MFMA GEMM: in(fp16)[N,128] @ Wsw + b, epilogue scales rows by dinv -> fp16 ============
__global__ __launch_bounds__(256) void gemm128_k(const __half* __restrict__ in,
                                                 const _Float16* __restrict__ Wsw,
                                                 const float* __restrict__ b,
                                                 const float* __restrict__ dinv,
                                                 __half* __restrict__ out) {
    int l = threadIdx.x & 63, w = threadIdx.x >> 6;
    int row0 = blockIdx.x * 64 + w * 16;
    int m = l & 15, q = l >> 4;
    int row = row0 + m;
    bool rok = row < N_NODES;
    const h8v* inp = (const h8v*)in;
    const h8v* wp = (const h8v*)Wsw;
    h8v az = {0, 0, 0, 0, 0, 0, 0, 0};
    h8v a[4];
#pragma unroll
    for (int kb = 0; kb < 4; kb++)
        a[kb] = rok ? inp[(row * 128 + kb * 32 + q * 8) >> 3] : az;
    float dv4[4];
#pragma unroll
    for (int r = 0; r < 4; r++) {
        int orow = row0 + q * 4 + r;
        dv4[r] = (orow < N_NODES) ? dinv[orow] : 0.f;
    }
#pragma unroll
    for (int ct = 0; ct < 8; ct++) {
        f4v acc = {0.f, 0.f, 0.f, 0.f};
#pragma unroll
        for (int kb = 0; kb < 4; kb++) {
            h8v bf = wp[((kb * 128 + ct * 16 + m) * 32 + q * 8) >> 3];
            acc = __builtin_amdgcn_mfma_f32_16x16x32_f16(a[kb], bf, acc, 0, 0, 0);
        }
        int col = ct * 16 + m;
        float bias = b[col];
#pragma unroll
        for (int r = 0; r < 4; r++) {
            int orow = row0 + q * 4 + r;
            if (orow < N_NODES) out[orow * 128 + col] = __float2half((acc[r] + bias) * dv4[r]);
        }
    }
}

// ============ resident-grid pull aggregation with implicit src-window sweep ============
// Exact baseline agg_k inner loop (wave-per-node, unroll-16 gathers) — but grid = GRES
// co-resident blocks, each looping 10 node-groups.  epack lists are window-sorted, so every
// wave's linear walk passes windows 0..6 in order; co-resident lockstep start => concurrent
// gathers share a ~2 MB L2-resident slice.  Worst case (drift) == baseline agg_k.
// MODE 0: + BN+ReLU -> outH fp16.  MODE 1: mu/logvar fp32 outs + zh fp16.
template <int MODE>
__global__ __launch_bounds__(256) void aggR_k(const __half* __restrict__ lin,
                                              const unsigned* __restrict__ nodeInfo,
                                              const unsigned* __restrict__ epack,
                                              const float* __restrict__ dinv,
                                              const float* __restrict__ sc,
                                              const float* __restrict__ sh,
                                              __half* __restrict__ outH,
                                              __half* __restrict__ zh,
                                              float* __restrict__ outp) {
    int tid = threadIdx.x;
    int t = tid & 63;
    const __half2* linv = (const __half2*)lin;
    for (int grp = blockIdx.x; grp < 12500; grp += GRES) {
        int n = grp * 4 + (tid >> 6);
        unsigned info = nodeInfo[n];
        int e0 = (int)(info & 0x1FFFFFu);
        int e1 = e0 + (int)(info >> 21);
        float dv = dinv[n];
        float2 self = __half22float2(linv[n * 64 + t]);
        float ax = self.x, ay = self.y;
        int e = e0;
        for (; e + 16 <= e1; e += 16) {
            unsigned r[16]; __half2 h[16];
#pragma unroll
            for (int j = 0; j < 16; j++) r[j] = epack[e + j];
#pragma unroll
            for (int j = 0; j < 16; j++) h[j] = linv[(int)(r[j] & 0xFFFFu) * 64 + t];
#pragma unroll
            for (int j = 0; j < 16; j++) {
                float w = __half2float(__ushort_as_half((ushort_t)(r[j] >> 16)));
                float2 f = __half22float2(h[j]);
                ax += w * f.x; ay += w * f.y;
            }
        }
        for (; e + 8 <= e1; e += 8) {
            unsigned r[8]; __half2 h[8];
#pragma unroll
            for (int j = 0; j < 8; j++) r[j] = epack[e + j];
#pragma unroll
            for (int j = 0; j < 8; j++) h[j] = linv[(int)(r[j] & 0xFFFFu) * 64 + t];
#pragma unroll
            for (int j = 0; j < 8; j++) {
                float w = __half2float(__ushort_as_half((ushort_t)(r[j] >> 16)));
                float2 f = __half22float2(h[j]);
                ax += w * f.x; ay += w * f.y;
            }
        }
        for (; e < e1; e++) {
            unsigned r = epack[e];
            float w = __half2float(__ushort_as_half((ushort_t)(r >> 16)));
            float2 f = __half22float2(linv[(int)(r & 0xFFFFu) * 64 + t]);
            ax += w * f.x; ay += w * f.y;
        }
        ax *= dv; ay *= dv;
        if (MODE == 0) {
            float2 s2 = *(const float2*)(sc + 2 * t);
            float2 h2 = *(const float2*)(sh + 2 * t);
            float o0 = fmaxf(ax * s2.x + h2.x, 0.f);
            float o1 = fmaxf(ay * s2.y + h2.y, 0.f);
            *(__half2*)(outH + n * 128 + 2 * t) = __floats2half2_rn(o0, o1);
        } else {
            if (t < 32) {
                *(float2*)(outp + OMU_OFF + n * 64 + 2 * t) = make_float2(ax, ay);
                ((__half2*)zh)[n * 32 + t] = __floats2half2_rn(ax, ay);
            } else {
                *(float2*)(outp + OLV_OFF + n * 64 + (2 * t - 64)) = make_float2(ax, ay);
            }
        }
    }
}

// ============ attention via MFMA: p = exp(tanh(zh @ Wa1 + ba1) @ Wa2 + ba2) ============
__global__ __launch_bounds__(256) void att_k(const __half* __restrict__ zh,
                                             const _Float16* __restrict__ Wasw,
                                             const float* __restrict__ ba1,
                                             const float* __restrict__ Wa2,
                                             const float* __restrict__ ba2,
                                             float* __restrict__ p, float* __restrict__ red) {
    __shared__ float rsum[4];
    int l = threadIdx.x & 63, w = threadIdx.x >> 6;
    int row0 = blockIdx.x * 64 + w * 16;
    int m = l & 15, q = l >> 4;
    int row = row0 + m;
    bool rok = row < N_NODES;
    const h8v* zp = (const h8v*)zh;
    const h8v* wp = (const h8v*)Wasw;
    h8v az = {0, 0, 0, 0, 0, 0, 0, 0};
    h8v a[2];
#pragma unroll
    for (int kb = 0; kb < 2; kb++)
        a[kb] = rok ? zp[(row * 64 + kb * 32 + q * 8) >> 3] : az;
    float ysum[4] = {0.f, 0.f, 0.f, 0.f};
#pragma unroll
    for (int ct = 0; ct < 8; ct++) {
        f4v acc = {0.f, 0.f, 0.f, 0.f};
#pragma unroll
        for (int kb = 0; kb < 2; kb++) {
            h8v bf = wp[((kb * 128 + ct * 16 + m) * 32 + q * 8) >> 3];
            acc = __builtin_amdgcn_mfma_f32_16x16x32_f16(a[kb], bf, acc, 0, 0, 0);
        }
        int col = ct * 16 + m;
        float bb = ba1[col], wa2 = Wa2[col];
#pragma unroll
        for (int r = 0; r < 4; r++) ysum[r] += tanhf(acc[r] + bb) * wa2;
    }
#pragma unroll
    for (int off = 1; off < 16; off <<= 1) {
#pragma unroll
        for (int r = 0; r < 4; r++) ysum[r] += __shfl_xor(ysum[r], off, 64);
    }
    float wsum = 0.f;
    if (m == 0) {
        float ba2v = ba2[0];
#pragma unroll
        for (int r = 0; r < 4; r++) {
            int orow = row0 + q * 4 + r;
            if (orow < N_NODES) {
                float pe = expf(ysum[r] + ba2v);
                p[orow] = pe;
                wsum += pe;
            }
        }
    }
    wsum += __shfl_xor(wsum, 16, 64);
    wsum += __shfl_xor(wsum, 32, 64);
    if (l == 0) rsum[w] = wsum;
    __syncthreads();
    if (threadIdx.x == 0)
        atomicAdd(&red[1], rsum[0] + rsum[1] + rsum[2] + rsum[3]);
}

// ============ pooling (4 groups of 64 per block) ============
__global__ __launch_bounds__(256) void pool_k(const __half* __restrict__ zh,
                                              const float* __restrict__ p,
                                              const int* __restrict__ batch,
                                              float* gpool, float* zsum, float* cnt,
                                              const int* __restrict__ flags) {
    int l = threadIdx.x & 63, g = threadIdx.x >> 6;
    int i64 = flags[1];
    int nstart = blockIdx.x * 256 + g * 64;
    float ag = 0.f, az = 0.f, c = 0.f;
    int cur = -1;
    for (int i = 0; i < 64; i++) {
        int n = nstart + i;
        if (n >= N_NODES) break;
        int b = clampi(batch[i64 ? 2 * n : n], 0, NB - 1);
        if (b != cur) {
            if (cur >= 0) {
                atomicAdd(&gpool[cur * 64 + l], ag);
                atomicAdd(&zsum[cur * 64 + l], az);
                if (l == 0) atomicAdd(&cnt[cur], c);
            }
            cur = b; ag = 0.f; az = 0.f; c = 0.f;
        }
        float pe = p[n];
        float zv = __half2float(zh[n * 64 + l]);
        ag += pe * zv; az += zv; c += 1.f;
    }
    if (cur >= 0) {
        atomicAdd(&gpool[cur * 64 + l], ag);
        atomicAdd(&zsum[cur * 64 + l], az);
        if (l == 0) atomicAdd(&cnt[cur], c);
    }
}

// ============ per-graph heads ============
__global__ __launch_bounds__(128) void head_k(const float* __restrict__ gpool,
                                              const float* __restrict__ zsum,
                                              const float* __restrict__ cnt,
                                              const float* __restrict__ red,
                                              const float* Wc1, const float* bc1,
                                              const float* Wc2, const float* bc2,
                                              const float* Wc3, const float* bc3,
                                              const float* Wn1, const float* bn1,
                                              const float* Wn2, const float* bn2,
                                              float* __restrict__ outp) {
    __shared__ float gsh[64], zm[64], p1[128], p2[64], n1[64];
    int b = blockIdx.x, t = threadIdx.x;
    float S = red[1];
    if (t < 64) {
        gsh[t] = gpool[b * 64 + t] / S;
        zm[t] = zsum[b * 64 + t] / fmaxf(cnt[b], 1.f);
    }
    __syncthreads();
    {
        float acc = bc1[t];
        for (int k = 0; k < 64; k++) acc += gsh[k] * Wc1[k * 128 + t];
        p1[t] = fmaxf(acc, 0.f);
    }
    __syncthreads();
    if (t < 64) {
        float acc = bc2[t];
        for (int k = 0; k < 128; k++) acc += p1[k] * Wc2[k * 64 + t];
        p2[t] = fmaxf(acc, 0.f);
    } else {
        int tt = t - 64;
        float acc = bn1[tt];
        for (int k = 0; k < 64; k++) acc += zm[k] * Wn1[k * 64 + tt];
        n1[tt] = fmaxf(acc, 0.f);
    }
    __syncthreads();
    if (t < NC) {
        float acc = bc3[t];
        for (int k = 0; k < 64; k++) acc += p2[k] * Wc3[k * 6 + t];
        outp[OPRED_OFF + b * 6 + t] = acc;
    }
    if (t == 64) {
        float acc = bn2[0];
        for (int k = 0; k < 64; k++) acc += n1[k] * Wn2[k];
        outp[ONOI_OFF + b] = 1.f / (1.f + expf(-acc));
    }
}

extern "C" void kernel_launch(void* const* d_in, const int* in_sizes, int n_in,
                              void* d_out, int out_size, void* d_ws, size_t ws_size,
                              hipStream_t stream) {
    const int*   ei    = (const int*)d_in[1];
    const int*   batch = (const int*)d_in[3];
    const float* x     = (const float*)d_in[0];
    const float* ew    = (const float*)d_in[2];
    const float* Win   = (const float*)d_in[4];
    const float* bin   = (const float*)d_in[5];
    const float* W1    = (const float*)d_in[6];
    const float* b1    = (const float*)d_in[7];
    const float* W2    = (const float*)d_in[8];
    const float* b2    = (const float*)d_in[9];
    const float* Wmu   = (const float*)d_in[10];
    const float* bmu   = (const float*)d_in[11];
    const float* Wlv   = (const float*)d_in[12];
    const float* blv   = (const float*)d_in[13];
    const float* g1    = (const float*)d_in[14];
    const float* be1   = (const float*)d_in[15];
    const float* rm1   = (const float*)d_in[16];
    const float* rv1   = (const float*)d_in[17];
    const float* g2    = (const float*)d_in[18];
    const float* be2   = (const float*)d_in[19];
    const float* rm2   = (const float*)d_in[20];
    const float* rv2   = (const float*)d_in[21];
    const float* Wa1   = (const float*)d_in[22];
    const float* ba1   = (const float*)d_in[23];
    const float* Wa2   = (const float*)d_in[24];
    const float* ba2   = (const float*)d_in[25];
    const float* Wc1   = (const float*)d_in[26];
    const float* bc1   = (const float*)d_in[27];
    const float* Wc2   = (const float*)d_in[28];
    const float* bc2   = (const float*)d_in[29];
    const float* Wc3   = (const float*)d_in[30];
    const float* bc3   = (const float*)d_in[31];
    const float* Wn1   = (const float*)d_in[32];
    const float* bn1   = (const float*)d_in[33];
    const float* Wn2   = (const float*)d_in[34];
    const float* bn2   = (const float*)d_in[35];

    float* outp = (float*)d_out;

    // workspace layout — identical to the 438µs-verified layout (~56 MB)
    char* ws = (char*)d_ws;
    size_t o = 0;
    auto alloc = [&](size_t bytes) { size_t r = o; o = (o + bytes + 511) & ~((size_t)511); return r; };
    int*      flags  = (int*)     (ws + alloc(16));
    float*    dinv   = (float*)   (ws + alloc(N_NODES * 4));
    unsigned* nodeInfo=(unsigned*)(ws + alloc(N_NODES * 4));
    int*      bcnt   = (int*)     (ws + alloc(NBUCK * 4));
    uint2*    recP   = (uint2*)   (ws + alloc((size_t)NBUCK * CAPB * 8));   // 14.5 MB
    unsigned* epack  = (unsigned*)(ws + alloc((size_t)NBUCK * CAPB * 4));   // 7.2 MB
    float*    pexp   = (float*)   (ws + alloc(N_NODES * 4));
    float*    Sd     = (float*)   (ws + alloc(N_NODES * 4));
    __half*   aggx   = (__half*)  (ws + alloc((size_t)N_NODES * 16 * 2));
    _Float16* W2sw   = (_Float16*)(ws + alloc(HF * HF * 2));
    _Float16* Wcsw   = (_Float16*)(ws + alloc(HF * HF * 2));
    _Float16* Wasw   = (_Float16*)(ws + alloc(LF * HF * 2));
    float*    Weff   = (float*)   (ws + alloc(16 * HF * 4));
    float*    beff   = (float*)   (ws + alloc(HF * 4));
    float*    bcat   = (float*)   (ws + alloc(HF * 4));
    float*    sc1    = (float*)   (ws + alloc(HF * 4));
    float*    sh1    = (float*)   (ws + alloc(HF * 4));
    float*    sc2    = (float*)   (ws + alloc(HF * 4));
    float*    sh2    = (float*)   (ws + alloc(HF * 4));
    float*    red    = (float*)   (ws + alloc(16));
    float*    gpool  = (float*)   (ws + alloc(NB * LF * 4));
    float*    zsum   = (float*)   (ws + alloc(NB * LF * 4));
    float*    cnt    = (float*)   (ws + alloc(NB * 4));
    __half*   bufA   = (__half*)  (ws + alloc((size_t)50048 * 128 * 2));
    __half*   bufB   = (__half*)  (ws + alloc((size_t)50048 * 128 * 2));
    __half*   zh     = (__half*)  (ws + alloc((size_t)50048 * 64 * 2));
    (void)ws_size; (void)n_in; (void)in_sizes; (void)out_size;

    const int GN = (N_NODES + 255) / 256;     // 196
    const int GP = (N_EDGES + EPB - 1) / EPB; // 782

    hipLaunchKernelGGL(init_k, dim3(GN), dim3(256), 0, stream,
                       ei, flags, bcnt, gpool, zsum, cnt, red,
                       W2sw, Wcsw, Wasw, bcat, sc1, sh1, sc2, sh2,
                       W2, Wmu, bmu, Wlv, blv, Wa1,
                       g1, be1, rm1, rv1, g2, be2, rm2, rv2);
    hipLaunchKernelGGL(weff_k, dim3(8), dim3(256), 0, stream, Win, bin, W1, b1, Weff, beff);
    hipLaunchKernelGGL(pass1_k, dim3(GP), dim3(256), 0, stream, ei, ew, bcnt, recP, flags);
    hipLaunchKernelGGL(pass2_k, dim3(NBUCK), dim3(256), 0, stream,
                       recP, bcnt, nodeInfo, dinv, epack);

    // encoder
    const int G16 = (N_NODES + 31) / 32;      // 1563
    const int GM  = (N_NODES + 63) / 64;      // 782
    hipLaunchKernelGGL(agg16_k, dim3(G16), dim3(256), 0, stream, x, epack, nodeInfo, dinv, aggx, Sd);
    hipLaunchKernelGGL(gemmbn_k, dim3(N_NODES / 16), dim3(128), 0, stream,
                       aggx, Sd, Weff, beff, sc1, sh1, bufA);                      // h1 -> A
    hipLaunchKernelGGL(gemm128_k, dim3(GM), dim3(256), 0, stream, bufA, W2sw, b2, dinv, bufB);  // t2 -> B
    hipLaunchKernelGGL((aggR_k<0>), dim3(GRES), dim3(256), 0, stream,
                       bufB, nodeInfo, epack, dinv, sc2, sh2,
                       bufA, (__half*)nullptr, (float*)nullptr);                   // h2 -> A
    hipLaunchKernelGGL(gemm128_k, dim3(GM), dim3(256), 0, stream, bufA, Wcsw, bcat, dinv, bufB);  // t3 -> B
    hipLaunchKernelGGL((aggR_k<1>), dim3(GRES), dim3(256), 0, stream,
                       bufB, nodeInfo, epack, dinv, (const float*)nullptr, (const float*)nullptr,
                       (__half*)nullptr, zh, outp);

    // attention + pooling + heads
    hipLaunchKernelGGL(att_k, dim3(GM), dim3(256), 0, stream, zh, Wasw, ba1, Wa2, ba2, pexp, red);
    hipLaunchKernelGGL(pool_k, dim3(GN), dim3(256), 0, stream, zh, pexp, batch, gpool, zsum, cnt, flags);
    hipLaunchKernelGGL(head_k, dim3(NB), dim3(128), 0, stream,
                       gpool, zsum, cnt, red, Wc1, bc1, Wc2, bc2, Wc3, bc3,
                       Wn1, bn1, Wn2, bn2, outp);
}

// Round 5
// 432.258 us; speedup vs baseline: 7.1125x; 1.0646x over previous
//
#include <hip/hip_runtime.h>
#include <hip/hip_fp16.h>

typedef unsigned short ushort_t;
typedef _Float16 h8v __attribute__((ext_vector_type(8)));
typedef float f4v __attribute__((ext_vector_type(4)));
typedef unsigned uint4a __attribute__((ext_vector_type(4), aligned(4)));   // 4B-aligned dwordx4

#define N_NODES 50000
#define N_EDGES 1600000
#define NB      64
#define HF      128
#define LF      64
#define NC      6
#define EPSBN   1e-5f
#define NBUCK   196          // dst buckets of 256 nodes
#define CAPB    9984         // per-bucket padded capacity (mean 8192 + per-node 4-align pad 768 + 11 sigma)
#define EPB     2048         // edges per pass1 block
#define GA      12500        // agg grid: 4 nodes/block

// output element offsets (fp32 out confirmed in round 3)
#define OPRED_OFF 0
#define OMU_OFF   384
#define OLV_OFF   3200384
#define ONOI_OFF  6400384

__device__ __forceinline__ int clampi(int v, int lo, int hi) {
    return v < lo ? lo : (v > hi ? hi : v);
}

// ============ init: flags, zero pools, fold BN, swizzle weights, fold Win@W1 (ex-weff) ============
__global__ void init_k(const int* ei_raw, int* flags,
                       int* bcnt, float* gpool, float* zsum, float* cnt, float* red,
                       _Float16* W2sw, _Float16* Wcsw, _Float16* Wasw,
                       float* bcat, float* sc1, float* sh1, float* sc2, float* sh2,
                       const float* W2,
                       const float* Wmu, const float* bmu, const float* Wlv, const float* blv,
                       const float* Wa1,
                       const float* g1, const float* be1, const float* rm1, const float* rv1,
                       const float* g2, const float* be2, const float* rm2, const float* rv2,
                       const float* Win, const float* bin, const float* W1, const float* b1,
                       float* Weff, float* beff) {
    int i = blockIdx.x * 256 + threadIdx.x;
    if (blockIdx.x == 0) {
        __shared__ int c1s;
        if (threadIdx.x == 0) c1s = 0;
        __syncthreads();
        if (ei_raw[2 * threadIdx.x + 1] != 0) atomicAdd(&c1s, 1);
        __syncthreads();
        if (threadIdx.x == 0) flags[1] = (c1s == 0) ? 1 : 0;
    }
    if (i < NBUCK) bcnt[i] = 0;
    if (i < NB * LF) { gpool[i] = 0.f; zsum[i] = 0.f; }
    if (i < NB) cnt[i] = 0.f;
    if (i < 4) red[i] = 0.f;
    if (i < HF * HF) {
        int k = i >> 7, c = i & 127;
        int idx = ((k >> 5) * 128 + c) * 32 + (k & 31);
        W2sw[idx] = (_Float16)W2[i];
        float wc = (c < 64) ? Wmu[k * 64 + c] : Wlv[k * 64 + (c - 64)];
        Wcsw[idx] = (_Float16)wc;
    }
    if (i < LF * HF) {
        int k = i >> 7, c = i & 127;
        int idx = ((k >> 5) * 128 + c) * 32 + (k & 31);
        Wasw[idx] = (_Float16)Wa1[i];
    }
    if (i < HF) {
        bcat[i] = (i < 64) ? bmu[i] : blv[i - 64];
        float s1 = g1[i] * rsqrtf(rv1[i] + EPSBN);
        sc1[i] = s1; sh1[i] = be1[i] - rm1[i] * s1;
        float s2 = g2[i] * rsqrtf(rv2[i] + EPSBN);
        sc2[i] = s2; sh2[i] = be2[i] - rm2[i] * s2;
    }
    // folded input layer: Weff = Win@W1 (16x128), beff = bin@W1 + b1
    if (i < 16 * 128) {
        int k = i >> 7, c = i & 127;
        float acc = 0.f;
        for (int j = 0; j < 128; j++) acc += Win[k * 128 + j] * W1[j * 128 + c];
        Weff[i] = acc;
    }
    if (i < 128) {
        float acc = b1[i];
        for (int j = 0; j < 128; j++) acc += bin[j] * W1[j * 128 + i];
        beff[i] = acc;
    }
}

// ============ pass 1: block-local LDS counting sort + run-append to padded buckets ============
__global__ __launch_bounds__(256) void pass1_k(const int* __restrict__ ei,
                                               const float* __restrict__ ew,
                                               int* __restrict__ bcnt,
                                               uint2* __restrict__ recP,
                                               const int* __restrict__ flags) {
    __shared__ uint2 stg[EPB];
    __shared__ int lh[NBUCK];
    __shared__ int lcur[NBUCK];
    __shared__ int gb[NBUCK];
    __shared__ int loff[256];
    int tid = threadIdx.x;
    for (int i = tid; i < NBUCK; i += 256) lh[i] = 0;
    __syncthreads();
    int e0 = blockIdx.x * EPB;
    int i64 = flags[1];
    uint2 myrec[8]; int myb[8];
#pragma unroll
    for (int j = 0; j < 8; j++) {
        int e = e0 + j * 256 + tid;
        if (e < N_EDGES) {
            int di = N_EDGES + e;
            int s = clampi(ei[i64 ? 2 * e : e], 0, N_NODES - 1);
            int d = clampi(ei[i64 ? 2 * di : di], 0, N_NODES - 1);
            myrec[j] = make_uint2((unsigned)s | ((unsigned)d << 16), __float_as_uint(ew[e]));
            myb[j] = d >> 8;
            atomicAdd(&lh[myb[j]], 1);
        } else myb[j] = -1;
    }
    __syncthreads();
    loff[tid] = (tid < NBUCK) ? lh[tid] : 0;
    __syncthreads();
    for (int dth = 1; dth < 256; dth <<= 1) {
        int x = (tid >= dth) ? loff[tid - dth] : 0;
        __syncthreads();
        loff[tid] += x;
        __syncthreads();
    }
    if (tid < NBUCK) lcur[tid] = loff[tid] - lh[tid];
    __syncthreads();
#pragma unroll
    for (int j = 0; j < 8; j++) {
        if (myb[j] >= 0) {
            int p = atomicAdd(&lcur[myb[j]], 1);
            stg[p] = myrec[j];
        }
    }
    if (tid < NBUCK) {
        int c = lh[tid];
        gb[tid] = (c > 0) ? atomicAdd(&bcnt[tid], c) : 0;
    }
    __syncthreads();
    int total = N_EDGES - e0; if (total > EPB) total = EPB;
    for (int idx = tid; idx < total; idx += 256) {
        uint2 r = stg[idx];
        int b = (int)(r.x >> 24);
        int within = idx - (loff[b] - lh[b]);
        int pos = gb[b] + within;
        if (pos < CAPB) recP[b * CAPB + pos] = r;
    }
}

// ============ pass 2 (merged): hist per (dst,src-window) + degree -> nodeInfo, dinv; scatter ============
// packed 4B records into epack sorted by (dst, src>>13).  Each node's segment start is padded
// to a multiple of 4 records (16B) so agg kernels can read epack with dwordx4; cnt in nodeInfo
// is the REAL count so pad slots are never read.  nodeInfo[n] = start | (cnt << 21).
__global__ __launch_bounds__(256) void pass2_k(const uint2* __restrict__ recP,
                                               const int* __restrict__ bcnt,
                                               unsigned* __restrict__ nodeInfo,
                                               float* __restrict__ dinv,
                                               unsigned* __restrict__ epack) {
    __shared__ int cw[256 * 8];    // per-(dst-local, window) count, then scatter cursor
    __shared__ float degs[256];
    __shared__ int off[256];
    int b = blockIdx.x, t = threadIdx.x;
    for (int i = t; i < 2048; i += 256) cw[i] = 0;
    degs[t] = 0.f;
    __syncthreads();
    int cb = bcnt[b]; if (cb > CAPB) cb = CAPB;
    int n0 = b * CAPB;
    for (int i = t; i < cb; i += 256) {
        uint2 r = recP[n0 + i];
        int dl = (r.x >> 16) & 255, s = (int)(r.x & 0xFFFFu);
        atomicAdd(&cw[dl * 8 + (s >> 13)], 1);
        atomicAdd(&degs[dl], __uint_as_float(r.y));
    }
    __syncthreads();
    int c[8]; int v = 0;
#pragma unroll
    for (int w = 0; w < 8; w++) { c[w] = cw[t * 8 + w]; v += c[w]; }
    int vp = (v + 3) & ~3;               // 16B-aligned segment size
    off[t] = vp;
    __syncthreads();
    for (int dth = 1; dth < 256; dth <<= 1) {
        int x = (t >= dth) ? off[t - dth] : 0;
        __syncthreads();
        off[t] += x;
        __syncthreads();
    }
    int excl = off[t] - vp;              // padded (aligned) start
    int run = excl;
#pragma unroll
    for (int w = 0; w < 8; w++) { cw[t * 8 + w] = run; run += c[w]; }
    int n = (b << 8) + t;
    if (n < N_NODES) {
        int cv = v > 2047 ? 2047 : v;
        nodeInfo[n] = (unsigned)(n0 + excl) | ((unsigned)cv << 21);
        dinv[n] = rsqrtf(1.f + degs[t]);
    }
    __syncthreads();
    for (int i = t; i < cb; i += 256) {
        uint2 r = recP[n0 + i];
        int dl = (r.x >> 16) & 255, s = (int)(r.x & 0xFFFFu);
        int p = atomicAdd(&cw[dl * 8 + (s >> 13)], 1);
        __half hw = __float2half(__uint_as_float(r.y));
        if (p < CAPB) epack[n0 + p] = (unsigned)s | ((unsigned)__half_as_ushort(hw) << 16);
    }
}

// ============ agg16: 16-dim aggregation of raw x (pre-linear), 8 lanes per node ============
// aggx[d] = dinv_d * (sum_e ew*dinv_s*x[s] + dinv_d*x[d]);  Sd = dinv_d*(sum ew*dinv_s + dinv_d)
__global__ __launch_bounds__(256) void agg16_k(const float* __restrict__ x,
                                               const unsigned* __restrict__ epack,
                                               const unsigned* __restrict__ nodeInfo,
                                               const float* __restrict__ dinv,
                                               __half* __restrict__ aggx,
                                               float* __restrict__ Sd) {
    int tid = threadIdx.x;
    int n = blockIdx.x * 32 + (tid >> 3);
    if (n >= N_NODES) return;
    int f = tid & 7;
    unsigned info = nodeInfo[n];
    int e0 = (int)(info & 0x1FFFFFu);
    int e1 = e0 + (int)(info >> 21);
    float dv = dinv[n];
    float2 xs = *(const float2*)(x + n * 16 + f * 2);
    float ax = dv * xs.x, ay = dv * xs.y;
    float ss = dv;
    int e = e0;
    for (; e + 8 <= e1; e += 8) {
        uint4a q0 = *(const uint4a*)(epack + e);
        uint4a q1 = *(const uint4a*)(epack + e + 4);
        unsigned r[8] = {q0[0], q0[1], q0[2], q0[3], q1[0], q1[1], q1[2], q1[3]};
        float2 v[8]; float w[8];
#pragma unroll
        for (int j = 0; j < 8; j++) {
            int s = (int)(r[j] & 0xFFFFu);
            w[j] = __half2float(__ushort_as_half((ushort_t)(r[j] >> 16))) * dinv[s];
            v[j] = *(const float2*)(x + s * 16 + f * 2);
        }
#pragma unroll
        for (int j = 0; j < 8; j++) {
            ax += w[j] * v[j].x; ay += w[j] * v[j].y; ss += w[j];
        }
    }
    for (; e < e1; e++) {
        unsigned r = epack[e];
        int s = (int)(r & 0xFFFFu);
        float w = __half2float(__ushort_as_half((ushort_t)(r >> 16))) * dinv[s];
        float2 v = *(const float2*)(x + s * 16 + f * 2);
        ax += w * v.x; ay += w * v.y; ss += w;
    }
    *(__half2*)(aggx + n * 16 + 2 * f) = __floats2half2_rn(ax * dv, ay * dv);
    if (f == 0) Sd[n] = dv * ss;
}

// ============ layer-1 linear + BN + ReLU: h1 = relu(sc1*(aggx@Weff + Sd*beff) + sh1) ============
__global__ __launch_bounds__(128) void gemmbn_k(const __half* __restrict__ aggx,
                                                const float* __restrict__ Sd,
                                                const float* __restrict__ Weff,
                                                const float* __restrict__ beff,
                                                const float* __restrict__ sc1,
                                                const float* __restrict__ sh1,
                                                __half* __restrict__ out) {
    __shared__ float xl[16 * 16];
    __shared__ float sdl[16];
    int tid = threadIdx.x;
    int row0 = blockIdx.x * 16;
    if (tid < 64) {
        int r = tid >> 2, k4 = tid & 3;
        int row = row0 + r;
        float4 v4 = make_float4(0.f, 0.f, 0.f, 0.f);
        if (row < N_NODES) {
            __half2 h0 = *(const __half2*)(aggx + row * 16 + k4 * 4);
            __half2 h1 = *(const __half2*)(aggx + row * 16 + k4 * 4 + 2);
            float2 f0 = __half22float2(h0), f1 = __half22float2(h1);
            v4 = make_float4(f0.x, f0.y, f1.x, f1.y);
        }
        *(float4*)(xl + r * 16 + k4 * 4) = v4;
    }
    if (tid < 16) {
        int row = row0 + tid;
        sdl[tid] = (row < N_NODES) ? Sd[row] : 0.f;
    }
    float wv[16];
#pragma unroll
    for (int k = 0; k < 16; k++) wv[k] = Weff[k * 128 + tid];
    float bias = beff[tid];
    float s1 = sc1[tid], h1v = sh1[tid];
    __syncthreads();
    for (int r = 0; r < 16; r++) {
        float acc = sdl[r] * bias;
#pragma unroll
        for (int k = 0; k < 16; k++) acc += xl[r * 16 + k] * wv[k];
        int row = row0 + r;
        if (row < N_NODES) {
            float o = fmaxf(acc * s1 + h1v, 0.f);
            out[row * 128 + tid] = __float2half(o);
        }
    }
}

// ============ MFMA GEMM: in(fp16)[N,128] @ Wsw + b, epilogue scales rows by dinv -> fp16 ============
__global__ __launch_bounds__(256) void gemm128_k(const __half* __restrict__ in,
                                                 const _Float16* __restrict__ Wsw,
                                                 const float* __restrict__ b,
                                                 const float* __restrict__ dinv,
                                                 __half* __restrict__ out) {
    int l = threadIdx.x & 63, w = threadIdx.x >> 6;
    int row0 = blockIdx.x * 64 + w * 16;
    int m = l & 15, q = l >> 4;
    int row = row0 + m;
    bool rok = row < N_NODES;
    const h8v* inp = (const h8v*)in;
    const h8v* wp = (const h8v*)Wsw;
    h8v az = {0, 0, 0, 0, 0, 0, 0, 0};
    h8v a[4];
#pragma unroll
    for (int kb = 0; kb < 4; kb++)
        a[kb] = rok ? inp[(row * 128 + kb * 32 + q * 8) >> 3] : az;
    float dv4[4];
#pragma unroll
    for (int r = 0; r < 4; r++) {
        int orow = row0 + q * 4 + r;
        dv4[r] = (orow < N_NODES) ? dinv[orow] : 0.f;
    }
#pragma unroll
    for (int ct = 0; ct < 8; ct++) {
        f4v acc = {0.f, 0.f, 0.f, 0.f};
#pragma unroll
        for (int kb = 0; kb < 4; kb++) {
            h8v bf = wp[((kb * 128 + ct * 16 + m) * 32 + q * 8) >> 3];
            acc = __builtin_amdgcn_mfma_f32_16x16x32_f16(a[kb], bf, acc, 0, 0, 0);
        }
        int col = ct * 16 + m;
        float bias = b[col];
#pragma unroll
        for (int r = 0; r < 4; r++) {
            int orow = row0 + q * 4 + r;
            if (orow < N_NODES) out[orow * 128 + col] = __float2half((acc[r] + bias) * dv4[r]);
        }
    }
}

// ============ aggregation over dinv-scaled rows t: out = dv*(sum ew*t[s] + t[d]) ============
// Baseline-proven structure: 12500 blocks, wave per node, unroll-16 gathers.
// epack segments are 16B-aligned (pass2 pad) -> dwordx4 record loads.
// MODE 0: + BN+ReLU -> outH fp16.  MODE 1: mu/logvar fp32 outs + zh fp16.
template <int MODE>
__global__ __launch_bounds__(256) void agg_k(const __half* __restrict__ lin,
                                             const unsigned* __restrict__ nodeInfo,
                                             const unsigned* __restrict__ epack,
                                             const float* __restrict__ dinv,
                                             const float* __restrict__ sc,
                                             const float* __restrict__ sh,
                                             __half* __restrict__ outH,
                                             __half* __restrict__ zh,
                                             float* __restrict__ outp) {
    int tid = threadIdx.x;
    int n = blockIdx.x * 4 + (tid >> 6);
    int t = tid & 63;
    const __half2* linv = (const __half2*)lin;
    unsigned info = nodeInfo[n];
    int e0 = (int)(info & 0x1FFFFFu);
    int e1 = e0 + (int)(info >> 21);
    float dv = dinv[n];
    float2 self = __half22float2(linv[n * 64 + t]);
    float ax = self.x, ay = self.y;
    int e = e0;
    for (; e + 16 <= e1; e += 16) {
        uint4a q0 = *(const uint4a*)(epack + e);
        uint4a q1 = *(const uint4a*)(epack + e + 4);
        uint4a q2 = *(const uint4a*)(epack + e + 8);
        uint4a q3 = *(const uint4a*)(epack + e + 12);
        unsigned r[16] = {q0[0], q0[1], q0[2], q0[3], q1[0], q1[1], q1[2], q1[3],
                          q2[0], q2[1], q2[2], q2[3], q3[0], q3[1], q3[2], q3[3]};
        __half2 h[16];
#pragma unroll
        for (int j = 0; j < 16; j++) h[j] = linv[(int)(r[j] & 0xFFFFu) * 64 + t];
#pragma unroll
        for (int j = 0; j < 16; j++) {
            float w = __half2float(__ushort_as_half((ushort_t)(r[j] >> 16)));
            float2 f = __half22float2(h[j]);
            ax += w * f.x; ay += w * f.y;
        }
    }
    for (; e + 8 <= e1; e += 8) {
        uint4a q0 = *(const uint4a*)(epack + e);
        uint4a q1 = *(const uint4a*)(epack + e + 4);
        unsigned r[8] = {q0[0], q0[1], q0[2], q0[3], q1[0], q1[1], q1[2], q1[3]};
        __half2 h[8];
#pragma unroll
        for (int j = 0; j < 8; j++) h[j] = linv[(int)(r[j] & 0xFFFFu) * 64 + t];
#pragma unroll
        for (int j = 0; j < 8; j++) {
            float w = __half2float(__ushort_as_half((ushort_t)(r[j] >> 16)));
            float2 f = __half22float2(h[j]);
            ax += w * f.x; ay += w * f.y;
        }
    }
    for (; e < e1; e++) {
        unsigned r = epack[e];
        float w = __half2float(__ushort_as_half((ushort_t)(r >> 16)));
        float2 f = __half22float2(linv[(int)(r & 0xFFFFu) * 64 + t]);
        ax += w * f.x; ay += w * f.y;
    }
    ax *= dv; ay *= dv;
    if (MODE == 0) {
        float2 s2 = *(const float2*)(sc + 2 * t);
        float2 h2 = *(const float2*)(sh + 2 * t);
        float o0 = fmaxf(ax * s2.x + h2.x, 0.f);
        float o1 = fmaxf(ay * s2.y + h2.y, 0.f);
        *(__half2*)(outH + n * 128 + 2 * t) = __floats2half2_rn(o0, o1);
    } else {
        if (t < 32) {
            *(float2*)(outp + OMU_OFF + n * 64 + 2 * t) = make_float2(ax, ay);
            ((__half2*)zh)[n * 32 + t] = __floats2half2_rn(ax, ay);
        } else {
            *(float2*)(outp + OLV_OFF + n * 64 + (2 * t - 64)) = make_float2(ax, ay);
        }
    }
}

// ============ attention via MFMA: p = exp(tanh(zh @ Wa1 + ba1) @ Wa2 + ba2) ============
__global__ __launch_bounds__(256) void att_k(const __half* __restrict__ zh,
                                             const _Float16* __restrict__ Wasw,
                                             const float* __restrict__ ba1,
                                             const float* __restrict__ Wa2,
                                             const float* __restrict__ ba2,
                                             float* __restrict__ p, float* __restrict__ red) {
    __shared__ float rsum[4];
    int l = threadIdx.x & 63, w = threadIdx.x >> 6;
    int row0 = blockIdx.x * 64 + w * 16;
    int m = l & 15, q = l >> 4;
    int row = row0 + m;
    bool rok = row < N_NODES;
    const h8v* zp = (const h8v*)zh;
    const h8v* wp = (const h8v*)Wasw;
    h8v az = {0, 0, 0, 0, 0, 0, 0, 0};
    h8v a[2];
#pragma unroll
    for (int kb = 0; kb < 2; kb++)
        a[kb] = rok ? zp[(row * 64 + kb * 32 + q * 8) >> 3] : az;
    float ysum[4] = {0.f, 0.f, 0.f, 0.f};
#pragma unroll
    for (int ct = 0; ct < 8; ct++) {
        f4v acc = {0.f, 0.f, 0.f, 0.f};
#pragma unroll
        for (int kb = 0; kb < 2; kb++) {
            h8v bf = wp[((kb * 128 + ct * 16 + m) * 32 + q * 8) >> 3];
            acc = __builtin_amdgcn_mfma_f32_16x16x32_f16(a[kb], bf, acc, 0, 0, 0);
        }
        int col = ct * 16 + m;
        float bb = ba1[col], wa2 = Wa2[col];
#pragma unroll
        for (int r = 0; r < 4; r++) ysum[r] += tanhf(acc[r] + bb) * wa2;
    }
#pragma unroll
    for (int off = 1; off < 16; off <<= 1) {
#pragma unroll
        for (int r = 0; r < 4; r++) ysum[r] += __shfl_xor(ysum[r], off, 64);
    }
    float wsum = 0.f;
    if (m == 0) {
        float ba2v = ba2[0];
#pragma unroll
        for (int r = 0; r < 4; r++) {
            int orow = row0 + q * 4 + r;
            if (orow < N_NODES) {
                float pe = expf(ysum[r] + ba2v);
                p[orow] = pe;
                wsum += pe;
            }
        }
    }
    wsum += __shfl_xor(wsum, 16, 64);
    wsum += __shfl_xor(wsum, 32, 64);
    if (l == 0) rsum[w] = wsum;
    __syncthreads();
    if (threadIdx.x == 0)
        atomicAdd(&red[1], rsum[0] + rsum[1] + rsum[2] + rsum[3]);
}

// ============ pooling (4 groups of 64 per block) ============
__global__ __launch_bounds__(256) void pool_k(const __half* __restrict__ zh,
                                              const float* __restrict__ p,
                                              const int* __restrict__ batch,
                                              float* __restrict__ gpool,
                                              float* __restrict__ zsum,
                                              float* __restrict__ cnt,
                                              const int* __restrict__ flags) {
    int l = threadIdx.x & 63, g = threadIdx.x >> 6;
    int i64 = flags[1];
    int nstart = blockIdx.x * 256 + g * 64;
    float ag = 0.f, az = 0.f, c = 0.f;
    int cur = -1;
    for (int i = 0; i < 64; i++) {
        int n = nstart + i;
        if (n >= N_NODES) break;
        int b = clampi(batch[i64 ? 2 * n : n], 0, NB - 1);
        if (b != cur) {
            if (cur >= 0) {
                atomicAdd(&gpool[cur * 64 + l], ag);
                atomicAdd(&zsum[cur * 64 + l], az);
                if (l == 0) atomicAdd(&cnt[cur], c);
            }
            cur = b; ag = 0.f; az = 0.f; c = 0.f;
        }
        float pe = p[n];
        float zv = __half2float(zh[n * 64 + l]);
        ag += pe * zv; az += zv; c += 1.f;
    }
    if (cur >= 0) {
        atomicAdd(&gpool[cur * 64 + l], ag);
        atomicAdd(&zsum[cur * 64 + l], az);
        if (l == 0) atomicAdd(&cnt[cur], c);
    }
}

// ============ per-graph heads ============
__global__ __launch_bounds__(128) void head_k(const float* __restrict__ gpool,
                                              const float* __restrict__ zsum,
                                              const float* __restrict__ cnt,
                                              const float* __restrict__ red,
                                              const float* Wc1, const float* bc1,
                                              const float* Wc2, const float* bc2,
                                              const float* Wc3, const float* bc3,
                                              const float* Wn1, const float* bn1,
                                              const float* Wn2, const float* bn2,
                                              float* __restrict__ outp) {
    __shared__ float gsh[64], zm[64], p1[128], p2[64], n1[64];
    int b = blockIdx.x, t = threadIdx.x;
    float S = red[1];
    if (t < 64) {
        gsh[t] = gpool[b * 64 + t] / S;
        zm[t] = zsum[b * 64 + t] / fmaxf(cnt[b], 1.f);
    }
    __syncthreads();
    {
        float acc = bc1[t];
        for (int k = 0; k < 64; k++) acc += gsh[k] * Wc1[k * 128 + t];
        p1[t] = fmaxf(acc, 0.f);
    }
    __syncthreads();
    if (t < 64) {
        float acc = bc2[t];
        for (int k = 0; k < 128; k++) acc += p1[k] * Wc2[k * 64 + t];
        p2[t] = fmaxf(acc, 0.f);
    } else {
        int tt = t - 64;
        float acc = bn1[tt];
        for (int k = 0; k < 64; k++) acc += zm[k] * Wn1[k * 64 + tt];
        n1[tt] = fmaxf(acc, 0.f);
    }
    __syncthreads();
    if (t < NC) {
        float acc = bc3[t];
        for (int k = 0; k < 64; k++) acc += p2[k] * Wc3[k * 6 + t];
        outp[OPRED_OFF + b * 6 + t] = acc;
    }
    if (t == 64) {
        float acc = bn2[0];
        for (int k = 0; k < 64; k++) acc += n1[k] * Wn2[k];
        outp[ONOI_OFF + b] = 1.f / (1.f + expf(-acc));
    }
}

extern "C" void kernel_launch(void* const* d_in, const int* in_sizes, int n_in,
                              void* d_out, int out_size, void* d_ws, size_t ws_size,
                              hipStream_t stream) {
    const int*   ei    = (const int*)d_in[1];
    const int*   batch = (const int*)d_in[3];
    const float* x     = (const float*)d_in[0];
    const float* ew    = (const float*)d_in[2];
    const float* Win   = (const float*)d_in[4];
    const float* bin   = (const float*)d_in[5];
    const float* W1    = (const float*)d_in[6];
    const float* b1    = (const float*)d_in[7];
    const float* W2    = (const float*)d_in[8];
    const float* b2    = (const float*)d_in[9];
    const float* Wmu   = (const float*)d_in[10];
    const float* bmu   = (const float*)d_in[11];
    const float* Wlv   = (const float*)d_in[12];
    const float* blv   = (const float*)d_in[13];
    const float* g1    = (const float*)d_in[14];
    const float* be1   = (const float*)d_in[15];
    const float* rm1   = (const float*)d_in[16];
    const float* rv1   = (const float*)d_in[17];
    const float* g2    = (const float*)d_in[18];
    const float* be2   = (const float*)d_in[19];
    const float* rm2   = (const float*)d_in[20];
    const float* rv2   = (const float*)d_in[21];
    const float* Wa1   = (const float*)d_in[22];
    const float* ba1   = (const float*)d_in[23];
    const float* Wa2   = (const float*)d_in[24];
    const float* ba2   = (const float*)d_in[25];
    const float* Wc1   = (const float*)d_in[26];
    const float* bc1   = (const float*)d_in[27];
    const float* Wc2   = (const float*)d_in[28];
    const float* bc2   = (const float*)d_in[29];
    const float* Wc3   = (const float*)d_in[30];
    const float* bc3   = (const float*)d_in[31];
    const float* Wn1   = (const float*)d_in[32];
    const float* bn1   = (const float*)d_in[33];
    const float* Wn2   = (const float*)d_in[34];
    const float* bn2   = (const float*)d_in[35];

    float* outp = (float*)d_out;

    // workspace layout (~57 MB; r0's 56.2 MB verified + 0.7 MB CAPB growth)
    char* ws = (char*)d_ws;
    size_t o = 0;
    auto alloc = [&](size_t bytes) { size_t r = o; o = (o + bytes + 511) & ~((size_t)511); return r; };
    int*      flags  = (int*)     (ws + alloc(16));
    float*    dinv   = (float*)   (ws + alloc(N_NODES * 4));
    unsigned* nodeInfo=(unsigned*)(ws + alloc(N_NODES * 4));
    int*      bcnt   = (int*)     (ws + alloc(NBUCK * 4));
    uint2*    recP   = (uint2*)   (ws + alloc((size_t)NBUCK * CAPB * 8));   // 14.9 MB
    unsigned* epack  = (unsigned*)(ws + alloc((size_t)NBUCK * CAPB * 4));   // 7.5 MB
    float*    pexp   = (float*)   (ws + alloc(N_NODES * 4));
    float*    Sd     = (float*)   (ws + alloc(N_NODES * 4));
    __half*   aggx   = (__half*)  (ws + alloc((size_t)N_NODES * 16 * 2));
    _Float16* W2sw   = (_Float16*)(ws + alloc(HF * HF * 2));
    _Float16* Wcsw   = (_Float16*)(ws + alloc(HF * HF * 2));
    _Float16* Wasw   = (_Float16*)(ws + alloc(LF * HF * 2));
    float*    Weff   = (float*)   (ws + alloc(16 * HF * 4));
    float*    beff   = (float*)   (ws + alloc(HF * 4));
    float*    bcat   = (float*)   (ws + alloc(HF * 4));
    float*    sc1    = (float*)   (ws + alloc(HF * 4));
    float*    sh1    = (float*)   (ws + alloc(HF * 4));
    float*    sc2    = (float*)   (ws + alloc(HF * 4));
    float*    sh2    = (float*)   (ws + alloc(HF * 4));
    float*    red    = (float*)   (ws + alloc(16));
    float*    gpool  = (float*)   (ws + alloc(NB * LF * 4));
    float*    zsum   = (float*)   (ws + alloc(NB * LF * 4));
    float*    cnt    = (float*)   (ws + alloc(NB * 4));
    __half*   bufA   = (__half*)  (ws + alloc((size_t)50048 * 128 * 2));
    __half*   bufB   = (__half*)  (ws + alloc((size_t)50048 * 128 * 2));
    __half*   zh     = (__half*)  (ws + alloc((size_t)50048 * 64 * 2));
    (void)ws_size; (void)n_in; (void)in_sizes; (void)out_size;

    const int GN = (N_NODES + 255) / 256;     // 196
    const int GP = (N_EDGES + EPB - 1) / EPB; // 782

    hipLaunchKernelGGL(init_k, dim3(GN), dim3(256), 0, stream,
                       ei, flags, bcnt, gpool, zsum, cnt, red,
                       W2sw, Wcsw, Wasw, bcat, sc1, sh1, sc2, sh2,
                       W2, Wmu, bmu, Wlv, blv, Wa1,
                       g1, be1, rm1, rv1, g2, be2, rm2, rv2,
                       Win, bin, W1, b1, Weff, beff);
    hipLaunchKernelGGL(pass1_k, dim3(GP), dim3(256), 0, stream, ei, ew, bcnt, recP, flags);
    hipLaunchKernelGGL(pass2_k, dim3(NBUCK), dim3(256), 0, stream,
                       recP, bcnt, nodeInfo, dinv, epack);

    // encoder
    const int G16 = (N_NODES + 31) / 32;      // 1563
    const int GM  = (N_NODES + 63) / 64;      // 782
    hipLaunchKernelGGL(agg16_k, dim3(G16), dim3(256), 0, stream, x, epack, nodeInfo, dinv, aggx, Sd);
    hipLaunchKernelGGL(gemmbn_k, dim3(N_NODES / 16), dim3(128), 0, stream,
                       aggx, Sd, Weff, beff, sc1, sh1, bufA);                      // h1 -> A
    hipLaunchKernelGGL(gemm128_k, dim3(GM), dim3(256), 0, stream, bufA, W2sw, b2, dinv, bufB);  // t2 -> B
    hipLaunchKernelGGL((agg_k<0>), dim3(GA), dim3(256), 0, stream,
                       bufB, nodeInfo, epack, dinv, sc2, sh2,
                       bufA, (__half*)nullptr, (float*)nullptr);                   // h2 -> A
    hipLaunchKernelGGL(gemm128_k, dim3(GM), dim3(256), 0, stream, bufA, Wcsw, bcat, dinv, bufB);  // t3 -> B
    hipLaunchKernelGGL((agg_k<1>), dim3(GA), dim3(256), 0, stream,
                       bufB, nodeInfo, epack, dinv, (const float*)nullptr, (const float*)nullptr,
                       (__half*)nullptr, zh, outp);

    // attention + pooling + heads
    hipLaunchKernelGGL(att_k, dim3(GM), dim3(256), 0, stream, zh, Wasw, ba1, Wa2, ba2, pexp, red);
    hipLaunchKernelGGL(pool_k, dim3(GN), dim3(256), 0, stream, zh, pexp, batch, gpool, zsum, cnt, flags);
    hipLaunchKernelGGL(head_k, dim3(NB), dim3(128), 0, stream,
                       gpool, zsum, cnt, red, Wc1, bc1, Wc2, bc2, Wc3, bc3,
                       Wn1, bn1, Wn2, bn2, outp);
}

// Round 6
// 431.026 us; speedup vs baseline: 7.1328x; 1.0029x over previous
//
#include <hip/hip_runtime.h>
#include <hip/hip_fp16.h>

typedef unsigned short ushort_t;
typedef _Float16 h8v __attribute__((ext_vector_type(8)));
typedef float f4v __attribute__((ext_vector_type(4)));
typedef unsigned uint4a __attribute__((ext_vector_type(4), aligned(4)));   // 4B-aligned dwordx4

#define N_NODES 50000
#define N_EDGES 1600000
#define NB      64
#define HF      128
#define LF      64
#define NC      6
#define EPSBN   1e-5f
#define NBUCK   196          // dst buckets of 256 nodes
#define CAPB    9984         // per-bucket padded capacity (mean 8192 + 4-align pad + 11 sigma)
#define EPB     2048         // edges per pass1 block
#define GA      12500        // agg grid: 4 nodes/block

// output element offsets (fp32 out confirmed in round 3)
#define OPRED_OFF 0
#define OMU_OFF   384
#define OLV_OFF   3200384
#define ONOI_OFF  6400384

__device__ __forceinline__ int clampi(int v, int lo, int hi) {
    return v < lo ? lo : (v > hi ? hi : v);
}

// ============ init: flags, zero pools, fold BN, swizzle weights, fold Win@W1 ============
__global__ void init_k(const int* ei_raw, int* flags,
                       int* bcnt, float* gpool, float* zsum, float* cnt, float* red,
                       _Float16* W2sw, _Float16* Wcsw, _Float16* Wasw,
                       float* bcat, float* sc1, float* sh1, float* sc2, float* sh2,
                       const float* W2,
                       const float* Wmu, const float* bmu, const float* Wlv, const float* blv,
                       const float* Wa1,
                       const float* g1, const float* be1, const float* rm1, const float* rv1,
                       const float* g2, const float* be2, const float* rm2, const float* rv2,
                       const float* Win, const float* bin, const float* W1, const float* b1,
                       float* Weff, float* beff) {
    int i = blockIdx.x * 256 + threadIdx.x;
    if (blockIdx.x == 0) {
        __shared__ int c1s;
        if (threadIdx.x == 0) c1s = 0;
        __syncthreads();
        if (ei_raw[2 * threadIdx.x + 1] != 0) atomicAdd(&c1s, 1);
        __syncthreads();
        if (threadIdx.x == 0) flags[1] = (c1s == 0) ? 1 : 0;
    }
    if (i < NBUCK) bcnt[i] = 0;
    if (i < NB * LF) { gpool[i] = 0.f; zsum[i] = 0.f; }
    if (i < NB) cnt[i] = 0.f;
    if (i < 4) red[i] = 0.f;
    if (i < HF * HF) {
        int k = i >> 7, c = i & 127;
        int idx = ((k >> 5) * 128 + c) * 32 + (k & 31);
        W2sw[idx] = (_Float16)W2[i];
        float wc = (c < 64) ? Wmu[k * 64 + c] : Wlv[k * 64 + (c - 64)];
        Wcsw[idx] = (_Float16)wc;
    }
    if (i < LF * HF) {
        int k = i >> 7, c = i & 127;
        int idx = ((k >> 5) * 128 + c) * 32 + (k & 31);
        Wasw[idx] = (_Float16)Wa1[i];
    }
    if (i < HF) {
        bcat[i] = (i < 64) ? bmu[i] : blv[i - 64];
        float s1 = g1[i] * rsqrtf(rv1[i] + EPSBN);
        sc1[i] = s1; sh1[i] = be1[i] - rm1[i] * s1;
        float s2 = g2[i] * rsqrtf(rv2[i] + EPSBN);
        sc2[i] = s2; sh2[i] = be2[i] - rm2[i] * s2;
    }
    // folded input layer: Weff = Win@W1 (16x128), beff = bin@W1 + b1
    if (i < 16 * 128) {
        int k = i >> 7, c = i & 127;
        float acc = 0.f;
        for (int j = 0; j < 128; j++) acc += Win[k * 128 + j] * W1[j * 128 + c];
        Weff[i] = acc;
    }
    if (i < 128) {
        float acc = b1[i];
        for (int j = 0; j < 128; j++) acc += bin[j] * W1[j * 128 + i];
        beff[i] = acc;
    }
}

// ============ pass 1: block-local LDS counting sort + run-append to padded buckets ============
__global__ __launch_bounds__(256) void pass1_k(const int* __restrict__ ei,
                                               const float* __restrict__ ew,
                                               int* __restrict__ bcnt,
                                               uint2* __restrict__ recP,
                                               const int* __restrict__ flags) {
    __shared__ uint2 stg[EPB];
    __shared__ int lh[NBUCK];
    __shared__ int lcur[NBUCK];
    __shared__ int gb[NBUCK];
    __shared__ int loff[256];
    int tid = threadIdx.x;
    for (int i = tid; i < NBUCK; i += 256) lh[i] = 0;
    __syncthreads();
    int e0 = blockIdx.x * EPB;
    int i64 = flags[1];
    uint2 myrec[8]; int myb[8];
#pragma unroll
    for (int j = 0; j < 8; j++) {
        int e = e0 + j * 256 + tid;
        if (e < N_EDGES) {
            int di = N_EDGES + e;
            int s = clampi(ei[i64 ? 2 * e : e], 0, N_NODES - 1);
            int d = clampi(ei[i64 ? 2 * di : di], 0, N_NODES - 1);
            myrec[j] = make_uint2((unsigned)s | ((unsigned)d << 16), __float_as_uint(ew[e]));
            myb[j] = d >> 8;
            atomicAdd(&lh[myb[j]], 1);
        } else myb[j] = -1;
    }
    __syncthreads();
    loff[tid] = (tid < NBUCK) ? lh[tid] : 0;
    __syncthreads();
    for (int dth = 1; dth < 256; dth <<= 1) {
        int x = (tid >= dth) ? loff[tid - dth] : 0;
        __syncthreads();
        loff[tid] += x;
        __syncthreads();
    }
    if (tid < NBUCK) lcur[tid] = loff[tid] - lh[tid];
    __syncthreads();
#pragma unroll
    for (int j = 0; j < 8; j++) {
        if (myb[j] >= 0) {
            int p = atomicAdd(&lcur[myb[j]], 1);
            stg[p] = myrec[j];
        }
    }
    if (tid < NBUCK) {
        int c = lh[tid];
        gb[tid] = (c > 0) ? atomicAdd(&bcnt[tid], c) : 0;
    }
    __syncthreads();
    int total = N_EDGES - e0; if (total > EPB) total = EPB;
    for (int idx = tid; idx < total; idx += 256) {
        uint2 r = stg[idx];
        int b = (int)(r.x >> 24);
        int within = idx - (loff[b] - lh[b]);
        int pos = gb[b] + within;
        if (pos < CAPB) recP[b * CAPB + pos] = r;
    }
}

// ============ pass 2 (merged): hist per (dst,src-window) + degree -> nodeInfo, dinv; scatter ============
// packed 4B records into epack sorted by (dst, src>>13).  Segment starts 16B-aligned (pad);
// cnt in nodeInfo is the REAL count so pad slots are never read.
__global__ __launch_bounds__(256) void pass2_k(const uint2* __restrict__ recP,
                                               const int* __restrict__ bcnt,
                                               unsigned* __restrict__ nodeInfo,
                                               float* __restrict__ dinv,
                                               unsigned* __restrict__ epack) {
    __shared__ int cw[256 * 8];    // per-(dst-local, window) count, then scatter cursor
    __shared__ float degs[256];
    __shared__ int off[256];
    int b = blockIdx.x, t = threadIdx.x;
    for (int i = t; i < 2048; i += 256) cw[i] = 0;
    degs[t] = 0.f;
    __syncthreads();
    int cb = bcnt[b]; if (cb > CAPB) cb = CAPB;
    int n0 = b * CAPB;
    for (int i = t; i < cb; i += 256) {
        uint2 r = recP[n0 + i];
        int dl = (r.x >> 16) & 255, s = (int)(r.x & 0xFFFFu);
        atomicAdd(&cw[dl * 8 + (s >> 13)], 1);
        atomicAdd(&degs[dl], __uint_as_float(r.y));
    }
    __syncthreads();
    int c[8]; int v = 0;
#pragma unroll
    for (int w = 0; w < 8; w++) { c[w] = cw[t * 8 + w]; v += c[w]; }
    int vp = (v + 3) & ~3;               // 16B-aligned segment size
    off[t] = vp;
    __syncthreads();
    for (int dth = 1; dth < 256; dth <<= 1) {
        int x = (t >= dth) ? off[t - dth] : 0;
        __syncthreads();
        off[t] += x;
        __syncthreads();
    }
    int excl = off[t] - vp;              // padded (aligned) start
    int run = excl;
#pragma unroll
    for (int w = 0; w < 8; w++) { cw[t * 8 + w] = run; run += c[w]; }
    int n = (b << 8) + t;
    if (n < N_NODES) {
        int cv = v > 2047 ? 2047 : v;
        nodeInfo[n] = (unsigned)(n0 + excl) | ((unsigned)cv << 21);
        dinv[n] = rsqrtf(1.f + degs[t]);
    }
    __syncthreads();
    for (int i = t; i < cb; i += 256) {
        uint2 r = recP[n0 + i];
        int dl = (r.x >> 16) & 255, s = (int)(r.x & 0xFFFFu);
        int p = atomicAdd(&cw[dl * 8 + (s >> 13)], 1);
        __half hw = __float2half(__uint_as_float(r.y));
        if (p < CAPB) epack[n0 + p] = (unsigned)s | ((unsigned)__half_as_ushort(hw) << 16);
    }
}

// ============ enc1: fused agg16 + layer-1 linear + BN + ReLU ============
// Phase 1 (= agg16): 32 nodes/block, 8 lanes/node, aggregate raw x into fp32 LDS rows + Sd.
// Phase 2 (= gemmbn): each thread computes 16 contiguous output cols for its node from LDS.
// out = relu(sc1*(aggx@Weff + Sd*beff) + sh1) -> fp16.  No aggx/Sd global roundtrip.
__global__ __launch_bounds__(256) void enc1_k(const float* __restrict__ x,
                                              const unsigned* __restrict__ epack,
                                              const unsigned* __restrict__ nodeInfo,
                                              const float* __restrict__ dinv,
                                              const float* __restrict__ Weff,
                                              const float* __restrict__ beff,
                                              const float* __restrict__ sc1,
                                              const float* __restrict__ sh1,
                                              __half* __restrict__ out) {
    __shared__ float xsh[32][16];
    __shared__ float sdsh[32];
    int tid = threadIdx.x;
    int nl = tid >> 3, f = tid & 7;
    int n = blockIdx.x * 32 + nl;
    bool valid = n < N_NODES;
    unsigned info = valid ? nodeInfo[n] : 0u;
    int e0 = (int)(info & 0x1FFFFFu);
    int e1 = e0 + (int)(info >> 21);
    float dv = valid ? dinv[n] : 0.f;
    float2 xs = valid ? *(const float2*)(x + n * 16 + f * 2) : make_float2(0.f, 0.f);
    float ax = dv * xs.x, ay = dv * xs.y;
    float ss = dv;
    int e = e0;
    for (; e + 8 <= e1; e += 8) {
        uint4a q0 = *(const uint4a*)(epack + e);
        uint4a q1 = *(const uint4a*)(epack + e + 4);
        unsigned r[8] = {q0[0], q0[1], q0[2], q0[3], q1[0], q1[1], q1[2], q1[3]};
        float2 v[8]; float w[8];
#pragma unroll
        for (int j = 0; j < 8; j++) {
            int s = (int)(r[j] & 0xFFFFu);
            w[j] = __half2float(__ushort_as_half((ushort_t)(r[j] >> 16))) * dinv[s];
            v[j] = *(const float2*)(x + s * 16 + f * 2);
        }
#pragma unroll
        for (int j = 0; j < 8; j++) {
            ax += w[j] * v[j].x; ay += w[j] * v[j].y; ss += w[j];
        }
    }
    for (; e < e1; e++) {
        unsigned r = epack[e];
        int s = (int)(r & 0xFFFFu);
        float w = __half2float(__ushort_as_half((ushort_t)(r >> 16))) * dinv[s];
        float2 v = *(const float2*)(x + s * 16 + f * 2);
        ax += w * v.x; ay += w * v.y; ss += w;
    }
    xsh[nl][2 * f] = ax * dv;
    xsh[nl][2 * f + 1] = ay * dv;
    if (f == 0) sdsh[nl] = dv * ss;
    __syncthreads();
    // phase 2: cols c = f*16 + j (contiguous per thread -> coalesced node-row writes)
    float sd = sdsh[nl];
    int cbase = f * 16;
    float acc[16];
#pragma unroll
    for (int j = 0; j < 16; j++) acc[j] = sd * beff[cbase + j];
#pragma unroll
    for (int k = 0; k < 16; k++) {
        float xv = xsh[nl][k];
        const float4* wrow = (const float4*)(Weff + k * 128 + cbase);
#pragma unroll
        for (int j4 = 0; j4 < 4; j4++) {
            float4 wv = wrow[j4];
            acc[4 * j4 + 0] += xv * wv.x;
            acc[4 * j4 + 1] += xv * wv.y;
            acc[4 * j4 + 2] += xv * wv.z;
            acc[4 * j4 + 3] += xv * wv.w;
        }
    }
    if (valid) {
        __half2* op = (__half2*)(out + n * 128 + cbase);
#pragma unroll
        for (int jj = 0; jj < 8; jj++) {
            int c = cbase + 2 * jj;
            float o0 = fmaxf(acc[2 * jj] * sc1[c] + sh1[c], 0.f);
            float o1 = fmaxf(acc[2 * jj + 1] * sc1[c + 1] + sh1[c + 1], 0.f);
            op[jj] = __floats2half2_rn(o0, o1);
        }
    }
}

// ============ MFMA GEMM: in(fp16)[N,128] @ Wsw + b, epilogue scales rows by dinv -> fp16 ============
__global__ __launch_bounds__(256) void gemm128_k(const __half* __restrict__ in,
                                                 const _Float16* __restrict__ Wsw,
                                                 const float* __restrict__ b,
                                                 const float* __restrict__ dinv,
                                                 __half* __restrict__ out) {
    int l = threadIdx.x & 63, w = threadIdx.x >> 6;
    int row0 = blockIdx.x * 64 + w * 16;
    int m = l & 15, q = l >> 4;
    int row = row0 + m;
    bool rok = row < N_NODES;
    const h8v* inp = (const h8v*)in;
    const h8v* wp = (const h8v*)Wsw;
    h8v az = {0, 0, 0, 0, 0, 0, 0, 0};
    h8v a[4];
#pragma unroll
    for (int kb = 0; kb < 4; kb++)
        a[kb] = rok ? inp[(row * 128 + kb * 32 + q * 8) >> 3] : az;
    float dv4[4];
#pragma unroll
    for (int r = 0; r < 4; r++) {
        int orow = row0 + q * 4 + r;
        dv4[r] = (orow < N_NODES) ? dinv[orow] : 0.f;
    }
#pragma unroll
    for (int ct = 0; ct < 8; ct++) {
        f4v acc = {0.f, 0.f, 0.f, 0.f};
#pragma unroll
        for (int kb = 0; kb < 4; kb++) {
            h8v bf = wp[((kb * 128 + ct * 16 + m) * 32 + q * 8) >> 3];
            acc = __builtin_amdgcn_mfma_f32_16x16x32_f16(a[kb], bf, acc, 0, 0, 0);
        }
        int col = ct * 16 + m;
        float bias = b[col];
#pragma unroll
        for (int r = 0; r < 4; r++) {
            int orow = row0 + q * 4 + r;
            if (orow < N_NODES) out[orow * 128 + col] = __float2half((acc[r] + bias) * dv4[r]);
        }
    }
}

// ============ aggregation over dinv-scaled rows t: out = dv*(sum ew*t[s] + t[d]) ============
// Baseline-proven: 12500 blocks, wave per node, unroll-16 dwordx4 record loads.
// MODE 0: + BN+ReLU -> outH fp16.  MODE 1: mu/logvar fp32 outs + zh fp16.
template <int MODE>
__global__ __launch_bounds__(256) void agg_k(const __half* __restrict__ lin,
                                             const unsigned* __restrict__ nodeInfo,
                                             const unsigned* __restrict__ epack,
                                             const float* __restrict__ dinv,
                                             const float* __restrict__ sc,
                                             const float* __restrict__ sh,
                                             __half* __restrict__ outH,
                                             __half* __restrict__ zh,
                                             float* __restrict__ outp) {
    int tid = threadIdx.x;
    int n = blockIdx.x * 4 + (tid >> 6);
    int t = tid & 63;
    const __half2* linv = (const __half2*)lin;
    unsigned info = nodeInfo[n];
    int e0 = (int)(info & 0x1FFFFFu);
    int e1 = e0 + (int)(info >> 21);
    float dv = dinv[n];
    float2 self = __half22float2(linv[n * 64 + t]);
    float ax = self.x, ay = self.y;
    int e = e0;
    for (; e + 16 <= e1; e += 16) {
        uint4a q0 = *(const uint4a*)(epack + e);
        uint4a q1 = *(const uint4a*)(epack + e + 4);
        uint4a q2 = *(const uint4a*)(epack + e + 8);
        uint4a q3 = *(const uint4a*)(epack + e + 12);
        unsigned r[16] = {q0[0], q0[1], q0[2], q0[3], q1[0], q1[1], q1[2], q1[3],
                          q2[0], q2[1], q2[2], q2[3], q3[0], q3[1], q3[2], q3[3]};
        __half2 h[16];
#pragma unroll
        for (int j = 0; j < 16; j++) h[j] = linv[(int)(r[j] & 0xFFFFu) * 64 + t];
#pragma unroll
        for (int j = 0; j < 16; j++) {
            float w = __half2float(__ushort_as_half((ushort_t)(r[j] >> 16)));
            float2 f = __half22float2(h[j]);
            ax += w * f.x; ay += w * f.y;
        }
    }
    for (; e + 8 <= e1; e += 8) {
        uint4a q0 = *(const uint4a*)(epack + e);
        uint4a q1 = *(const uint4a*)(epack + e + 4);
        unsigned r[8] = {q0[0], q0[1], q0[2], q0[3], q1[0], q1[1], q1[2], q1[3]};
        __half2 h[8];
#pragma unroll
        for (int j = 0; j < 8; j++) h[j] = linv[(int)(r[j] & 0xFFFFu) * 64 + t];
#pragma unroll
        for (int j = 0; j < 8; j++) {
            float w = __half2float(__ushort_as_half((ushort_t)(r[j] >> 16)));
            float2 f = __half22float2(h[j]);
            ax += w * f.x; ay += w * f.y;
        }
    }
    for (; e < e1; e++) {
        unsigned r = epack[e];
        float w = __half2float(__ushort_as_half((ushort_t)(r >> 16)));
        float2 f = __half22float2(linv[(int)(r & 0xFFFFu) * 64 + t]);
        ax += w * f.x; ay += w * f.y;
    }
    ax *= dv; ay *= dv;
    if (MODE == 0) {
        float2 s2 = *(const float2*)(sc + 2 * t);
        float2 h2 = *(const float2*)(sh + 2 * t);
        float o0 = fmaxf(ax * s2.x + h2.x, 0.f);
        float o1 = fmaxf(ay * s2.y + h2.y, 0.f);
        *(__half2*)(outH + n * 128 + 2 * t) = __floats2half2_rn(o0, o1);
    } else {
        if (t < 32) {
            *(float2*)(outp + OMU_OFF + n * 64 + 2 * t) = make_float2(ax, ay);
            ((__half2*)zh)[n * 32 + t] = __floats2half2_rn(ax, ay);
        } else {
            *(float2*)(outp + OLV_OFF + n * 64 + (2 * t - 64)) = make_float2(ax, ay);
        }
    }
}

// ============ attention via MFMA + fused pooling ============
// Phase 1: p = exp(tanh(zh @ Wa1 + ba1) @ Wa2 + ba2) for the block's 64 rows -> LDS + red[1].
// Phase 2 (= old pool_k): strip-accumulate pe*z, z, count into per-graph sums (batch sorted).
__global__ __launch_bounds__(256) void att_k(const __half* __restrict__ zh,
                                             const _Float16* __restrict__ Wasw,
                                             const float* __restrict__ ba1,
                                             const float* __restrict__ Wa2,
                                             const float* __restrict__ ba2,
                                             const int* __restrict__ batch,
                                             const int* __restrict__ flags,
                                             float* __restrict__ gpool,
                                             float* __restrict__ zsum,
                                             float* __restrict__ cnt,
                                             float* __restrict__ red) {
    __shared__ float rsum[4];
    __shared__ float pes[64];
    int l = threadIdx.x & 63, w = threadIdx.x >> 6;
    int row0 = blockIdx.x * 64 + w * 16;
    int m = l & 15, q = l >> 4;
    int row = row0 + m;
    bool rok = row < N_NODES;
    const h8v* zp = (const h8v*)zh;
    const h8v* wp = (const h8v*)Wasw;
    h8v az = {0, 0, 0, 0, 0, 0, 0, 0};
    h8v a[2];
#pragma unroll
    for (int kb = 0; kb < 2; kb++)
        a[kb] = rok ? zp[(row * 64 + kb * 32 + q * 8) >> 3] : az;
    float ysum[4] = {0.f, 0.f, 0.f, 0.f};
#pragma unroll
    for (int ct = 0; ct < 8; ct++) {
        f4v acc = {0.f, 0.f, 0.f, 0.f};
#pragma unroll
        for (int kb = 0; kb < 2; kb++) {
            h8v bf = wp[((kb * 128 + ct * 16 + m) * 32 + q * 8) >> 3];
            acc = __builtin_amdgcn_mfma_f32_16x16x32_f16(a[kb], bf, acc, 0, 0, 0);
        }
        int col = ct * 16 + m;
        float bb = ba1[col], wa2 = Wa2[col];
#pragma unroll
        for (int r = 0; r < 4; r++) ysum[r] += tanhf(acc[r] + bb) * wa2;
    }
#pragma unroll
    for (int off = 1; off < 16; off <<= 1) {
#pragma unroll
        for (int r = 0; r < 4; r++) ysum[r] += __shfl_xor(ysum[r], off, 64);
    }
    float wsum = 0.f;
    if (m == 0) {
        float ba2v = ba2[0];
#pragma unroll
        for (int r = 0; r < 4; r++) {
            int orow = row0 + q * 4 + r;
            float pe = 0.f;
            if (orow < N_NODES) {
                pe = expf(ysum[r] + ba2v);
                wsum += pe;
            }
            pes[w * 16 + q * 4 + r] = pe;
        }
    }
    wsum += __shfl_xor(wsum, 16, 64);
    wsum += __shfl_xor(wsum, 32, 64);
    if (l == 0) rsum[w] = wsum;
    __syncthreads();
    if (threadIdx.x == 0)
        atomicAdd(&red[1], rsum[0] + rsum[1] + rsum[2] + rsum[3]);
    // ---- phase 2: pooling over this block's 64 rows (16 per wave) ----
    int i64 = flags[1];
    int nstart = blockIdx.x * 64 + w * 16;
    float ag = 0.f, azv = 0.f, c = 0.f;
    int cur = -1;
    for (int i = 0; i < 16; i++) {
        int n = nstart + i;
        if (n >= N_NODES) break;
        int b = clampi(batch[i64 ? 2 * n : n], 0, NB - 1);
        if (b != cur) {
            if (cur >= 0) {
                atomicAdd(&gpool[cur * 64 + l], ag);
                atomicAdd(&zsum[cur * 64 + l], azv);
                if (l == 0) atomicAdd(&cnt[cur], c);
            }
            cur = b; ag = 0.f; azv = 0.f; c = 0.f;
        }
        float pe = pes[w * 16 + i];
        float zv = __half2float(zh[n * 64 + l]);
        ag += pe * zv; azv += zv; c += 1.f;
    }
    if (cur >= 0) {
        atomicAdd(&gpool[cur * 64 + l], ag);
        atomicAdd(&zsum[cur * 64 + l], azv);
        if (l == 0) atomicAdd(&cnt[cur], c);
    }
}

// ============ per-graph heads ============
__global__ __launch_bounds__(128) void head_k(const float* __restrict__ gpool,
                                              const float* __restrict__ zsum,
                                              const float* __restrict__ cnt,
                                              const float* __restrict__ red,
                                              const float* Wc1, const float* bc1,
                                              const float* Wc2, const float* bc2,
                                              const float* Wc3, const float* bc3,
                                              const float* Wn1, const float* bn1,
                                              const float* Wn2, const float* bn2,
                                              float* __restrict__ outp) {
    __shared__ float gsh[64], zm[64], p1[128], p2[64], n1[64];
    int b = blockIdx.x, t = threadIdx.x;
    float S = red[1];
    if (t < 64) {
        gsh[t] = gpool[b * 64 + t] / S;
        zm[t] = zsum[b * 64 + t] / fmaxf(cnt[b], 1.f);
    }
    __syncthreads();
    {
        float acc = bc1[t];
        for (int k = 0; k < 64; k++) acc += gsh[k] * Wc1[k * 128 + t];
        p1[t] = fmaxf(acc, 0.f);
    }
    __syncthreads();
    if (t < 64) {
        float acc = bc2[t];
        for (int k = 0; k < 128; k++) acc += p1[k] * Wc2[k * 64 + t];
        p2[t] = fmaxf(acc, 0.f);
    } else {
        int tt = t - 64;
        float acc = bn1[tt];
        for (int k = 0; k < 64; k++) acc += zm[k] * Wn1[k * 64 + tt];
        n1[tt] = fmaxf(acc, 0.f);
    }
    __syncthreads();
    if (t < NC) {
        float acc = bc3[t];
        for (int k = 0; k < 64; k++) acc += p2[k] * Wc3[k * 6 + t];
        outp[OPRED_OFF + b * 6 + t] = acc;
    }
    if (t == 64) {
        float acc = bn2[0];
        for (int k = 0; k < 64; k++) acc += n1[k] * Wn2[k];
        outp[ONOI_OFF + b] = 1.f / (1.f + expf(-acc));
    }
}

extern "C" void kernel_launch(void* const* d_in, const int* in_sizes, int n_in,
                              void* d_out, int out_size, void* d_ws, size_t ws_size,
                              hipStream_t stream) {
    const int*   ei    = (const int*)d_in[1];
    const int*   batch = (const int*)d_in[3];
    const float* x     = (const float*)d_in[0];
    const float* ew    = (const float*)d_in[2];
    const float* Win   = (const float*)d_in[4];
    const float* bin   = (const float*)d_in[5];
    const float* W1    = (const float*)d_in[6];
    const float* b1    = (const float*)d_in[7];
    const float* W2    = (const float*)d_in[8];
    const float* b2    = (const float*)d_in[9];
    const float* Wmu   = (const float*)d_in[10];
    const float* bmu   = (const float*)d_in[11];
    const float* Wlv   = (const float*)d_in[12];
    const float* blv   = (const float*)d_in[13];
    const float* g1    = (const float*)d_in[14];
    const float* be1   = (const float*)d_in[15];
    const float* rm1   = (const float*)d_in[16];
    const float* rv1   = (const float*)d_in[17];
    const float* g2    = (const float*)d_in[18];
    const float* be2   = (const float*)d_in[19];
    const float* rm2   = (const float*)d_in[20];
    const float* rv2   = (const float*)d_in[21];
    const float* Wa1   = (const float*)d_in[22];
    const float* ba1   = (const float*)d_in[23];
    const float* Wa2   = (const float*)d_in[24];
    const float* ba2   = (const float*)d_in[25];
    const float* Wc1   = (const float*)d_in[26];
    const float* bc1   = (const float*)d_in[27];
    const float* Wc2   = (const float*)d_in[28];
    const float* bc2   = (const float*)d_in[29];
    const float* Wc3   = (const float*)d_in[30];
    const float* bc3   = (const float*)d_in[31];
    const float* Wn1   = (const float*)d_in[32];
    const float* bn1   = (const float*)d_in[33];
    const float* Wn2   = (const float*)d_in[34];
    const float* bn2   = (const float*)d_in[35];

    float* outp = (float*)d_out;

    // workspace layout (~55 MB; aggx/Sd/pexp removed after fusions)
    char* ws = (char*)d_ws;
    size_t o = 0;
    auto alloc = [&](size_t bytes) { size_t r = o; o = (o + bytes + 511) & ~((size_t)511); return r; };
    int*      flags  = (int*)     (ws + alloc(16));
    float*    dinv   = (float*)   (ws + alloc(N_NODES * 4));
    unsigned* nodeInfo=(unsigned*)(ws + alloc(N_NODES * 4));
    int*      bcnt   = (int*)     (ws + alloc(NBUCK * 4));
    uint2*    recP   = (uint2*)   (ws + alloc((size_t)NBUCK * CAPB * 8));   // 14.9 MB
    unsigned* epack  = (unsigned*)(ws + alloc((size_t)NBUCK * CAPB * 4));   // 7.5 MB
    _Float16* W2sw   = (_Float16*)(ws + alloc(HF * HF * 2));
    _Float16* Wcsw   = (_Float16*)(ws + alloc(HF * HF * 2));
    _Float16* Wasw   = (_Float16*)(ws + alloc(LF * HF * 2));
    float*    Weff   = (float*)   (ws + alloc(16 * HF * 4));
    float*    beff   = (float*)   (ws + alloc(HF * 4));
    float*    bcat   = (float*)   (ws + alloc(HF * 4));
    float*    sc1    = (float*)   (ws + alloc(HF * 4));
    float*    sh1    = (float*)   (ws + alloc(HF * 4));
    float*    sc2    = (float*)   (ws + alloc(HF * 4));
    float*    sh2    = (float*)   (ws + alloc(HF * 4));
    float*    red    = (float*)   (ws + alloc(16));
    float*    gpool  = (float*)   (ws + alloc(NB * LF * 4));
    float*    zsum   = (float*)   (ws + alloc(NB * LF * 4));
    float*    cnt    = (float*)   (ws + alloc(NB * 4));
    __half*   bufA   = (__half*)  (ws + alloc((size_t)50048 * 128 * 2));
    __half*   bufB   = (__half*)  (ws + alloc((size_t)50048 * 128 * 2));
    __half*   zh     = (__half*)  (ws + alloc((size_t)50048 * 64 * 2));
    (void)ws_size; (void)n_in; (void)in_sizes; (void)out_size;

    const int GN = (N_NODES + 255) / 256;     // 196
    const int GP = (N_EDGES + EPB - 1) / EPB; // 782

    hipLaunchKernelGGL(init_k, dim3(GN), dim3(256), 0, stream,
                       ei, flags, bcnt, gpool, zsum, cnt, red,
                       W2sw, Wcsw, Wasw, bcat, sc1, sh1, sc2, sh2,
                       W2, Wmu, bmu, Wlv, blv, Wa1,
                       g1, be1, rm1, rv1, g2, be2, rm2, rv2,
                       Win, bin, W1, b1, Weff, beff);
    hipLaunchKernelGGL(pass1_k, dim3(GP), dim3(256), 0, stream, ei, ew, bcnt, recP, flags);
    hipLaunchKernelGGL(pass2_k, dim3(NBUCK), dim3(256), 0, stream,
                       recP, bcnt, nodeInfo, dinv, epack);

    // encoder
    const int G16 = (N_NODES + 31) / 32;      // 1563
    const int GM  = (N_NODES + 63) / 64;      // 782
    hipLaunchKernelGGL(enc1_k, dim3(G16), dim3(256), 0, stream,
                       x, epack, nodeInfo, dinv, Weff, beff, sc1, sh1, bufA);      // h1 -> A
    hipLaunchKernelGGL(gemm128_k, dim3(GM), dim3(256), 0, stream, bufA, W2sw, b2, dinv, bufB);  // t2 -> B
    hipLaunchKernelGGL((agg_k<0>), dim3(GA), dim3(256), 0, stream,
                       bufB, nodeInfo, epack, dinv, sc2, sh2,
                       bufA, (__half*)nullptr, (float*)nullptr);                   // h2 -> A
    hipLaunchKernelGGL(gemm128_k, dim3(GM), dim3(256), 0, stream, bufA, Wcsw, bcat, dinv, bufB);  // t3 -> B
    hipLaunchKernelGGL((agg_k<1>), dim3(GA), dim3(256), 0, stream,
                       bufB, nodeInfo, epack, dinv, (const float*)nullptr, (const float*)nullptr,
                       (__half*)nullptr, zh, outp);

    // attention + pooling (fused) + heads
    hipLaunchKernelGGL(att_k, dim3(GM), dim3(256), 0, stream,
                       zh, Wasw, ba1, Wa2, ba2, batch, flags, gpool, zsum, cnt, red);
    hipLaunchKernelGGL(head_k, dim3(NB), dim3(128), 0, stream,
                       gpool, zsum, cnt, red, Wc1, bc1, Wc2, bc2, Wc3, bc3,
                       Wn1, bn1, Wn2, bn2, outp);
}